// Round 3
// baseline (629.401 us; speedup 1.0000x reference)
//
#include <hip/hip_runtime.h>

typedef __bf16 bf16x4 __attribute__((ext_vector_type(4)));
typedef __bf16 bf16x8 __attribute__((ext_vector_type(8)));
typedef float  f32x4  __attribute__((ext_vector_type(4)));

constexpr int N_NODES = 50000;
constexpr int N_EDGES = 640000;
constexpr int NTILES  = 98;     // ceil(50000/512)
constexpr int NB_EDGE = 2500;   // edge blocks; 10000 tiles / 2500 = exactly 4 tiles each

__device__ __forceinline__ float leaky(float v) { return v >= 0.f ? v : 0.15f * v; }

// ---------------------------------------------------------------------------
// Prep: pack all weight matrices into MFMA B-fragment order (bf16) and fold
// the linear algebra:  M = eW2 @ nW[128:],  c = nb + eb2 @ nW[128:]
// ---------------------------------------------------------------------------
__global__ void prep_kernel(
    const float* __restrict__ e1W1, const float* __restrict__ e1b1,
    const float* __restrict__ e1W2, const float* __restrict__ e1b2,
    const float* __restrict__ n1W,  const float* __restrict__ n1b,
    const float* __restrict__ e2W1, const float* __restrict__ e2b1,
    const float* __restrict__ e2W2, const float* __restrict__ e2b2,
    const float* __restrict__ n2W,  const float* __restrict__ n2b,
    const float* __restrict__ muW,  const float* __restrict__ mub,
    const float* __restrict__ lvW,  const float* __restrict__ lvb,
    __bf16* __restrict__ packE, __bf16* __restrict__ packN1,
    __bf16* __restrict__ packN2, __bf16* __restrict__ packH,
    float* __restrict__ ebias, float* __restrict__ c1, float* __restrict__ c2,
    float* __restrict__ hbias)
{
    int bid = blockIdx.x;
    int lane = threadIdx.x;          // 64 threads
    int quad = lane >> 4, low = lane & 15;

    if (bid < 32) {                                   // edge B pack [64 x 256]
        int ct = bid >> 1, kt = bid & 1;
        for (int j = 0; j < 8; ++j) {
            int k = kt * 32 + quad * 8 + j;
            int n = ct * 16 + low;
            float v = (n < 128) ? e1W1[k * 128 + n] : e2W1[k * 128 + (n - 128)];
            packE[((ct * 2 + kt) * 64 + lane) * 8 + j] = (__bf16)v;
        }
    } else if (bid < 160) {                           // node1 / node2 B pack [256 x 128]
        bool is1 = bid < 96;
        int tile = bid - (is1 ? 32 : 96);
        const float* nW  = is1 ? n1W  : n2W;
        const float* eW2 = is1 ? e1W2 : e2W2;
        __bf16* dst = is1 ? packN1 : packN2;
        int ct = tile >> 3, kt = tile & 7;
        for (int j = 0; j < 8; ++j) {
            int k = kt * 32 + quad * 8 + j;
            int n = ct * 16 + low;
            float v;
            if (k < 128) {
                v = nW[k * 128 + n];
            } else {
                int i = k - 128;
                float acc = 0.f;
                for (int k2 = 0; k2 < 128; ++k2)
                    acc += eW2[i * 128 + k2] * nW[(128 + k2) * 128 + n];
                v = acc;
            }
            dst[((ct * 8 + kt) * 64 + lane) * 8 + j] = (__bf16)v;
        }
    } else if (bid < 192) {                           // head B pack [128 x 128]
        int tile = bid - 160;
        int ct = tile >> 2, kt = tile & 3;
        for (int j = 0; j < 8; ++j) {
            int k = kt * 32 + quad * 8 + j;
            int n = ct * 16 + low;
            float v = (n < 64) ? muW[k * 64 + n] : lvW[k * 64 + (n - 64)];
            packH[((ct * 4 + kt) * 64 + lane) * 8 + j] = (__bf16)v;
        }
    } else if (bid == 192 || bid == 193) {            // c1 / c2
        const float* nW  = (bid == 192) ? n1W  : n2W;
        const float* nb  = (bid == 192) ? n1b  : n2b;
        const float* eb2 = (bid == 192) ? e1b2 : e2b2;
        float* dst = (bid == 192) ? c1 : c2;
        for (int rep = 0; rep < 2; ++rep) {
            int j = lane + rep * 64;
            float acc = nb[j];
            for (int k = 0; k < 128; ++k)
                acc += eb2[k] * nW[(128 + k) * 128 + j];
            dst[j] = acc;
        }
    } else {                                          // biases
        for (int rep = 0; rep < 4; ++rep) {
            int j = lane + rep * 64;
            ebias[j] = (j < 128) ? e1b1[j] : e2b1[j - 128];
        }
        for (int rep = 0; rep < 2; ++rep) {
            int j = lane + rep * 64;
            hbias[j] = (j < 64) ? mub[j] : lvb[j - 64];
        }
    }
}

// --------------------------- counting sort by dst ---------------------------
__global__ void hist_kernel(const int* __restrict__ dstp, int* __restrict__ deg) {
    int e = blockIdx.x * 256 + threadIdx.x;
    if (e < N_EDGES) atomicAdd(&deg[dstp[e]], 1);
}

__global__ void scan_a(const int* __restrict__ deg, int* __restrict__ offs,
                       int* __restrict__ tileSum, float* __restrict__ degf) {
    __shared__ int s[512];
    int t = threadIdx.x, i = blockIdx.x * 512 + t;
    int v = (i < N_NODES) ? deg[i] : 0;
    if (i < N_NODES) degf[i] = (float)v;       // folded from old scan_c
    s[t] = v; __syncthreads();
    for (int off = 1; off < 512; off <<= 1) {
        int x = (t >= off) ? s[t - off] : 0;
        __syncthreads();
        s[t] += x;
        __syncthreads();
    }
    if (i < N_NODES) offs[i] = s[t] - v;       // exclusive within tile
    if (t == 511) tileSum[blockIdx.x] = s[511];
}

// scan_b folded into scatter_kernel: each block redundantly scans the 98 tile
// sums in LDS instead of a serial 1-block launch.
__global__ void scatter_kernel(const int* __restrict__ dstp, const int* __restrict__ offs,
                               const int* __restrict__ tileSum,
                               int* __restrict__ cursor, int* __restrict__ sorted,
                               int* __restrict__ sdst) {
    __shared__ int s[128];
    __shared__ int toff[128];
    int t = threadIdx.x;
    int v = 0;
    if (t < 128) { v = (t < NTILES) ? tileSum[t] : 0; s[t] = v; }
    __syncthreads();
    for (int off = 1; off < 128; off <<= 1) {
        int x = (t < 128 && t >= off) ? s[t - off] : 0;
        __syncthreads();
        if (t < 128) s[t] += x;
        __syncthreads();
    }
    if (t < 128) toff[t] = s[t] - v;           // exclusive tile offsets
    __syncthreads();
    int e = blockIdx.x * 256 + t;
    if (e < N_EDGES) {
        int d = dstp[e];
        int p = offs[d] + toff[d >> 9] + atomicAdd(&cursor[d], 1);
        sorted[p] = e;
        sdst[p] = d;
    }
}

// ---------------------------------------------------------------------------
// Edge kernel v9b: occupancy build — target 4 blocks/CU (16 waves).
//  * Registers: GEMM1 split into two rt-halves (C1[2][4] = 32 AGPR live, not
//    64); immediate atomics (no deferred state). Combined VGPR+AGPR target
//    <=128 -> __launch_bounds__(256, 4).
//  * LDS: run metadata in registers (all waves compute it redundantly from
//    identical sdst loads). run->dst table via ONE ds_permute push: every
//    lane of run j pushes md_c to dest lane j; colliding writers carry the
//    same value, so the collision is benign. Lanes >= nruns get garbage,
//    guarded by run < nruns at every consumer.
//  * As/Lb at stride 64 bytes*2 with XOR swizzle byte ^= (row&7)<<4 -> all
//    b128/b64 accesses evenly bank-distributed.
//    LDS = 8192 (As) + 32768 (Lb) = 40960 B exactly = 4 blocks/CU.
//  * 2 barriers/iter, both protecting only As (Lb is wave-local).
// ---------------------------------------------------------------------------
__global__ __launch_bounds__(256, 4) void edge_kernel(
    const float* __restrict__ edge_attr,
    const int* __restrict__ sorted, const int* __restrict__ sdst,
    const __bf16* __restrict__ packE,
    const float* __restrict__ ebias, float* __restrict__ S)
{
    __shared__ alignas(16) __bf16 As[64 * 64];         // 8192 B, swizzled
    __shared__ alignas(16) __bf16 Lball[4 * 64 * 64];  // 32768 B, per-wave slices

    int tid = threadIdx.x;
    int w = tid >> 6, lane = tid & 63;
    int quad = lane >> 4, low = lane & 15;
    int r = tid >> 2, c0 = (tid & 3) * 16;

    auto swz = [](int row, int cb) { return row * 128 + (cb ^ ((row & 7) << 4)); };

    // hoist weight fragments + bias into registers
    bf16x8 bfragE[2][4];
    #pragma unroll
    for (int kt = 0; kt < 2; ++kt)
        #pragma unroll
        for (int ct = 0; ct < 4; ++ct)
            bfragE[kt][ct] = *reinterpret_cast<const bf16x8*>(
                packE + (((w * 4 + ct) * 2 + kt) * 64 + lane) * 8);
    float bias_c[4];
    #pragma unroll
    for (int ct = 0; ct < 4; ++ct) bias_c[ct] = ebias[w * 64 + ct * 16 + low];

    char* AsB = reinterpret_cast<char*>(As);
    char* LbB = reinterpret_cast<char*>(&Lball[w * 4096]);

    constexpr int STRIDE = NB_EDGE * 64;
    int e0 = blockIdx.x * 64;

    // ---- prologue: tile 0 attr + dst, tile 1 indices ----
    float4 f0, f1, f2, f3;
    int md_c, ei_n, md_n;
    {
        int ei = sorted[e0 + r];
        md_c = sdst[e0 + lane];
        const float4* ap = reinterpret_cast<const float4*>(edge_attr + (size_t)ei * 64 + c0);
        f0 = ap[0]; f1 = ap[1]; f2 = ap[2]; f3 = ap[3];
    }
    ei_n = sorted[e0 + STRIDE + r];
    md_n = sdst[e0 + STRIDE + lane];

    #pragma unroll 1
    for (int it = 0; it < 4; ++it) {
        // ---- stage As from registers (bf16, swizzled stride-64) ----
        {
            bf16x8 v0, v1;
            v0[0]=(__bf16)f0.x; v0[1]=(__bf16)f0.y; v0[2]=(__bf16)f0.z; v0[3]=(__bf16)f0.w;
            v0[4]=(__bf16)f1.x; v0[5]=(__bf16)f1.y; v0[6]=(__bf16)f1.z; v0[7]=(__bf16)f1.w;
            v1[0]=(__bf16)f2.x; v1[1]=(__bf16)f2.y; v1[2]=(__bf16)f2.z; v1[3]=(__bf16)f2.w;
            v1[4]=(__bf16)f3.x; v1[5]=(__bf16)f3.y; v1[6]=(__bf16)f3.z; v1[7]=(__bf16)f3.w;
            *reinterpret_cast<bf16x8*>(AsB + swz(r, c0 * 2))      = v0;
            *reinterpret_cast<bf16x8*>(AsB + swz(r, c0 * 2 + 16)) = v1;
        }

        // ---- run structure, per-wave in registers (md_c identical across waves) ----
        int dp = __shfl_up(md_c, 1);
        bool flag = (lane > 0) && (md_c != dp);
        unsigned long long mask = __ballot(flag);
        int nruns = __popcll(mask) + 1;
        // run id of this lane's edge
        int rid = __popcll(mask & ((1ull << lane) - 1ull)) + (flag ? 1 : 0);
        // run->dst table: all lanes of run j push identical md_c to lane j
        int vdst = __builtin_amdgcn_ds_permute(rid << 2, md_c);

        __syncthreads();                               // B: As published

        // ---- prefetch: tile it+1 attr, tile it+2 indices ----
        float4 g0{}, g1{}, g2{}, g3{};
        if (it < 3) {
            const float4* gp = reinterpret_cast<const float4*>(
                edge_attr + (size_t)ei_n * 64 + c0);
            g0 = gp[0]; g1 = gp[1]; g2 = gp[2]; g3 = gp[3];
        }
        int ei_nn = 0, md_nn = 0;
        if (it < 2) {
            int eo = e0 + (it + 2) * STRIDE;
            ei_nn = sorted[eo + r];
            md_nn = sdst[eo + lane];
        }

        // ---- GEMM1 in two rt-halves (32 AGPR live instead of 64) ----
        #pragma unroll
        for (int half = 0; half < 2; ++half) {
            f32x4 C1[2][4] = {};
            #pragma unroll
            for (int kt = 0; kt < 2; ++kt)
                #pragma unroll
                for (int rti = 0; rti < 2; ++rti) {
                    int rt = half * 2 + rti;
                    bf16x8 a = *reinterpret_cast<const bf16x8*>(
                        AsB + swz(rt * 16 + low, kt * 64 + quad * 16));
                    #pragma unroll
                    for (int ct = 0; ct < 4; ++ct)
                        C1[rti][ct] = __builtin_amdgcn_mfma_f32_16x16x32_bf16(
                            a, bfragE[kt][ct], C1[rti][ct], 0, 0, 0);
                }
            // epilogue: bias + leaky -> wave-local Lb (col-major, swizzled)
            #pragma unroll
            for (int rti = 0; rti < 2; ++rti)
                #pragma unroll
                for (int ct = 0; ct < 4; ++ct) {
                    int rt = half * 2 + rti;
                    bf16x4 v;
                    #pragma unroll
                    for (int rr = 0; rr < 4; ++rr)
                        v[rr] = (__bf16)leaky(C1[rti][ct][rr] + bias_c[ct]);
                    *reinterpret_cast<bf16x4*>(
                        LbB + swz(ct * 16 + low, rt * 32 + quad * 8)) = v;
                }
        }

        // ---- GEMM2: S_part = R @ L, run-selector A built from mask ----
        for (int rt2 = 0; rt2 * 16 < nruns; ++rt2) {
            int target = rt2 * 16 + low;
            f32x4 C2[4] = {};
            #pragma unroll
            for (int kt = 0; kt < 2; ++kt) {
                int bsh = 63 - kt * 32 - quad * 8;
                bf16x8 a;
                #pragma unroll
                for (int j = 0; j < 8; ++j) {
                    int ride = __popcll(mask << (bsh - j));   // run id of edge kt*32+quad*8+j
                    a[j] = (ride == target) ? (__bf16)1.0f : (__bf16)0.0f;
                }
                #pragma unroll
                for (int ct = 0; ct < 4; ++ct) {
                    bf16x8 b = *reinterpret_cast<const bf16x8*>(
                        LbB + swz(ct * 16 + low, kt * 64 + quad * 16));
                    C2[ct] = __builtin_amdgcn_mfma_f32_16x16x32_bf16(a, b, C2[ct], 0, 0, 0);
                }
            }
            int node4[4];
            #pragma unroll
            for (int rr = 0; rr < 4; ++rr)
                node4[rr] = __shfl(vdst, rt2 * 16 + quad * 4 + rr);
            #pragma unroll
            for (int ct = 0; ct < 4; ++ct) {
                int col = w * 64 + ct * 16 + low;
                #pragma unroll
                for (int rr = 0; rr < 4; ++rr) {
                    int run = rt2 * 16 + quad * 4 + rr;
                    if (run < nruns && (unsigned)node4[rr] < (unsigned)N_NODES)
                        unsafeAtomicAdd(&S[(size_t)node4[rr] * 256 + col], C2[ct][rr]);
                }
            }
        }

        __syncthreads();                               // E': As reads done; drains loads+atomics

        // ---- rotate pipeline registers ----
        f0 = g0; f1 = g1; f2 = g2; f3 = g3;
        md_c = md_n; ei_n = ei_nn; md_n = md_nn;
    }
}

// ---------------------------------------------------------------------------
// Fused node pipeline: conv1 -> conv2 -> heads in ONE kernel.
// Row-local: h[r]=leaky(deg*x[r]@Wt1+deg*c1 + S1[r]@M1); same for g; out=g@[muW|lvW].
// h,g hand off through wave-local LDS (row-major bf16, stride 152).
// h is stored pre-scaled by deg (folds conv2's row scaling).
// ---------------------------------------------------------------------------
__global__ __launch_bounds__(256) void node_fused(
    const float* __restrict__ x, const float* __restrict__ S,
    const float* __restrict__ degf,
    const __bf16* __restrict__ packN1, const __bf16* __restrict__ packN2,
    const __bf16* __restrict__ packH,
    const float* __restrict__ c1, const float* __restrict__ c2,
    const float* __restrict__ hbias,
    float* __restrict__ out)
{
    constexpr int HS = 152;                        // row stride (elements), 304 B
    __shared__ __bf16 Hs[4][16 * HS];              // 19456 B
    int w = threadIdx.x >> 6, lane = threadIdx.x & 63;
    int quad = lane >> 4, low = lane & 15;
    int rb = blockIdx.x * 64 + w * 16;

    int arow = rb + low;
    if (arow >= N_NODES) arow = N_NODES - 1;
    float ds = degf[arow];
    const float* xrow = x + (size_t)arow * 128;
    const float* Srow = S + (size_t)arow * 256;

    float deg4[4];
    #pragma unroll
    for (int rr = 0; rr < 4; ++rr) {
        int row = rb + quad * 4 + rr;
        deg4[rr] = degf[row < N_NODES ? row : N_NODES - 1];
    }

    __bf16* Hw = Hs[w];

    // ---- conv1: C = [deg*x | S1] @ packN1 ----
    f32x4 C[8] = {};
    #pragma unroll
    for (int kt = 0; kt < 8; ++kt) {
        const float* base = (kt < 4) ? (xrow + kt * 32 + quad * 8)
                                     : (Srow + (kt - 4) * 32 + quad * 8);
        float4 p0 = *reinterpret_cast<const float4*>(base);
        float4 p1 = *reinterpret_cast<const float4*>(base + 4);
        float m = (kt < 4) ? ds : 1.f;
        bf16x8 a;
        a[0]=(__bf16)(p0.x*m); a[1]=(__bf16)(p0.y*m); a[2]=(__bf16)(p0.z*m); a[3]=(__bf16)(p0.w*m);
        a[4]=(__bf16)(p1.x*m); a[5]=(__bf16)(p1.y*m); a[6]=(__bf16)(p1.z*m); a[7]=(__bf16)(p1.w*m);
        #pragma unroll
        for (int ct = 0; ct < 8; ++ct) {
            bf16x8 b = *reinterpret_cast<const bf16x8*>(packN1 + ((ct * 8 + kt) * 64 + lane) * 8);
            C[ct] = __builtin_amdgcn_mfma_f32_16x16x32_bf16(a, b, C[ct], 0, 0, 0);
        }
    }
    // epilogue: store deg*h (pre-scaled for conv2) row-major bf16
    #pragma unroll
    for (int ct = 0; ct < 8; ++ct) {
        int col = ct * 16 + low;
        float cb = c1[col];
        #pragma unroll
        for (int rr = 0; rr < 4; ++rr) {
            float v = leaky(C[ct][rr] + deg4[rr] * cb);
            Hw[(quad * 4 + rr) * HS + col] = (__bf16)(v * deg4[rr]);
        }
    }

    // ---- conv2: C2 = [deg*h | S2] @ packN2 ----
    f32x4 C2[8] = {};
    #pragma unroll
    for (int kt = 0; kt < 8; ++kt) {
        bf16x8 a;
        if (kt < 4) {
            a = *reinterpret_cast<const bf16x8*>(&Hw[low * HS + kt * 32 + quad * 8]);
        } else {
            const float* base = Srow + 128 + (kt - 4) * 32 + quad * 8;
            float4 p0 = *reinterpret_cast<const float4*>(base);
            float4 p1 = *reinterpret_cast<const float4*>(base + 4);
            a[0]=(__bf16)p0.x; a[1]=(__bf16)p0.y; a[2]=(__bf16)p0.z; a[3]=(__bf16)p0.w;
            a[4]=(__bf16)p1.x; a[5]=(__bf16)p1.y; a[6]=(__bf16)p1.z; a[7]=(__bf16)p1.w;
        }
        #pragma unroll
        for (int ct = 0; ct < 8; ++ct) {
            bf16x8 b = *reinterpret_cast<const bf16x8*>(packN2 + ((ct * 8 + kt) * 64 + lane) * 8);
            C2[ct] = __builtin_amdgcn_mfma_f32_16x16x32_bf16(a, b, C2[ct], 0, 0, 0);
        }
    }
    // epilogue: store g (unscaled) over the same LDS
    #pragma unroll
    for (int ct = 0; ct < 8; ++ct) {
        int col = ct * 16 + low;
        float cb = c2[col];
        #pragma unroll
        for (int rr = 0; rr < 4; ++rr) {
            float v = leaky(C2[ct][rr] + deg4[rr] * cb);
            Hw[(quad * 4 + rr) * HS + col] = (__bf16)v;
        }
    }

    // ---- heads: C3 = g @ [muW|lvW] ----
    f32x4 C3[8] = {};
    #pragma unroll
    for (int kt = 0; kt < 4; ++kt) {
        bf16x8 a = *reinterpret_cast<const bf16x8*>(&Hw[low * HS + kt * 32 + quad * 8]);
        #pragma unroll
        for (int ct = 0; ct < 8; ++ct) {
            bf16x8 b = *reinterpret_cast<const bf16x8*>(packH + ((ct * 4 + kt) * 64 + lane) * 8);
            C3[ct] = __builtin_amdgcn_mfma_f32_16x16x32_bf16(a, b, C3[ct], 0, 0, 0);
        }
    }
    #pragma unroll
    for (int ct = 0; ct < 8; ++ct) {
        int col = ct * 16 + low;
        float hb = hbias[col];
        #pragma unroll
        for (int rr = 0; rr < 4; ++rr) {
            int row = rb + quad * 4 + rr;
            if (row >= N_NODES) continue;
            float v = C3[ct][rr] + hb;
            if (col < 64) out[(size_t)row * 64 + col] = v;
            else          out[(size_t)N_NODES * 64 + (size_t)row * 64 + (col - 64)] = v;
        }
    }
}

// ---------------------------------------------------------------------------
extern "C" void kernel_launch(void* const* d_in, const int* in_sizes, int n_in,
                              void* d_out, int out_size, void* d_ws, size_t ws_size,
                              hipStream_t stream)
{
    const float* x     = (const float*)d_in[0];
    const int*   eidx  = (const int*)  d_in[1];
    const float* eattr = (const float*)d_in[2];
    const float* e1W1 = (const float*)d_in[3];
    const float* e1b1 = (const float*)d_in[4];
    const float* e1W2 = (const float*)d_in[5];
    const float* e1b2 = (const float*)d_in[6];
    const float* n1W  = (const float*)d_in[7];
    const float* n1b  = (const float*)d_in[8];
    const float* e2W1 = (const float*)d_in[9];
    const float* e2b1 = (const float*)d_in[10];
    const float* e2W2 = (const float*)d_in[11];
    const float* e2b2 = (const float*)d_in[12];
    const float* n2W  = (const float*)d_in[13];
    const float* n2b  = (const float*)d_in[14];
    const float* muW  = (const float*)d_in[15];
    const float* mub  = (const float*)d_in[16];
    const float* lvW  = (const float*)d_in[17];
    const float* lvb  = (const float*)d_in[18];

    const int* dstp = eidx + N_EDGES;   // edge_index row 1

    char* ws = (char*)d_ws;
    size_t off = 0;
    auto alloc = [&](size_t bytes) -> void* {
        void* p = ws + off;
        off = (off + bytes + 1023) & ~(size_t)1023;
        return p;
    };
    float* S       = (float*)alloc((size_t)N_NODES * 256 * 4);   // [N][256] S1|S2
    float* h       = (float*)alloc((size_t)N_NODES * 128 * 4);   // unused (layout keep)
    float* g       = (float*)alloc((size_t)N_NODES * 128 * 4);   // backs sdst
    int*   deg     = (int*)  alloc((size_t)N_NODES * 4);
    int*   cursor  = (int*)  alloc((size_t)N_NODES * 4);
    int*   offs    = (int*)  alloc((size_t)N_NODES * 4);
    float* degf    = (float*)alloc((size_t)N_NODES * 4);
    int*   sorted  = (int*)  alloc((size_t)N_EDGES * 4);
    int*   tileSum = (int*)  alloc(NTILES * 4);
    __bf16* packE  = (__bf16*)alloc(32 * 64 * 8 * 2);
    __bf16* packN1 = (__bf16*)alloc(64 * 64 * 8 * 2);
    __bf16* packN2 = (__bf16*)alloc(64 * 64 * 8 * 2);
    __bf16* packH  = (__bf16*)alloc(32 * 64 * 8 * 2);
    float* ebias   = (float*)alloc(256 * 4);
    float* c1      = (float*)alloc(128 * 4);
    float* c2      = (float*)alloc(128 * 4);
    float* hbias   = (float*)alloc(128 * 4);
    (void)ws_size; (void)in_sizes; (void)n_in; (void)out_size; (void)h;

    int* sdst = (int*)g;   // g region is free scratch (node pipeline fused)

    hipMemsetAsync(S, 0, (size_t)N_NODES * 256 * 4, stream);
    // deg + cursor are adjacent 1024-padded allocations -> one memset
    hipMemsetAsync(deg, 0, 2 * (((size_t)N_NODES * 4 + 1023) & ~(size_t)1023), stream);

    prep_kernel<<<195, 64, 0, stream>>>(e1W1, e1b1, e1W2, e1b2, n1W, n1b,
                                        e2W1, e2b1, e2W2, e2b2, n2W, n2b,
                                        muW, mub, lvW, lvb,
                                        packE, packN1, packN2, packH,
                                        ebias, c1, c2, hbias);

    hist_kernel<<<N_EDGES / 256, 256, 0, stream>>>(dstp, deg);
    scan_a<<<NTILES, 512, 0, stream>>>(deg, offs, tileSum, degf);
    scatter_kernel<<<N_EDGES / 256, 256, 0, stream>>>(dstp, offs, tileSum, cursor, sorted, sdst);

    edge_kernel<<<NB_EDGE, 256, 0, stream>>>(eattr, sorted, sdst, packE, ebias, S);

    node_fused<<<(N_NODES + 63) / 64, 256, 0, stream>>>(
        x, S, degf, packN1, packN2, packH, c1, c2, hbias, (float*)d_out);
}

// Round 4
// 527.498 us; speedup vs baseline: 1.1932x; 1.1932x over previous
//
#include <hip/hip_runtime.h>

typedef __bf16 bf16x4 __attribute__((ext_vector_type(4)));
typedef __bf16 bf16x8 __attribute__((ext_vector_type(8)));
typedef float  f32x4  __attribute__((ext_vector_type(4)));

constexpr int N_NODES = 50000;
constexpr int N_EDGES = 640000;
constexpr int NTILES  = 98;     // ceil(50000/512)
constexpr int NB_EDGE = 2500;   // edge blocks; 10000 tiles / 2500 = exactly 4 tiles each

__device__ __forceinline__ float leaky(float v) { return v >= 0.f ? v : 0.15f * v; }

// ---------------------------------------------------------------------------
// Prep: pack all weight matrices into MFMA B-fragment order (bf16) and fold
// the linear algebra:  M = eW2 @ nW[128:],  c = nb + eb2 @ nW[128:]
// ---------------------------------------------------------------------------
__global__ void prep_kernel(
    const float* __restrict__ e1W1, const float* __restrict__ e1b1,
    const float* __restrict__ e1W2, const float* __restrict__ e1b2,
    const float* __restrict__ n1W,  const float* __restrict__ n1b,
    const float* __restrict__ e2W1, const float* __restrict__ e2b1,
    const float* __restrict__ e2W2, const float* __restrict__ e2b2,
    const float* __restrict__ n2W,  const float* __restrict__ n2b,
    const float* __restrict__ muW,  const float* __restrict__ mub,
    const float* __restrict__ lvW,  const float* __restrict__ lvb,
    __bf16* __restrict__ packE, __bf16* __restrict__ packN1,
    __bf16* __restrict__ packN2, __bf16* __restrict__ packH,
    float* __restrict__ ebias, float* __restrict__ c1, float* __restrict__ c2,
    float* __restrict__ hbias)
{
    int bid = blockIdx.x;
    int lane = threadIdx.x;          // 64 threads
    int quad = lane >> 4, low = lane & 15;

    if (bid < 32) {                                   // edge B pack [64 x 256]
        int ct = bid >> 1, kt = bid & 1;
        for (int j = 0; j < 8; ++j) {
            int k = kt * 32 + quad * 8 + j;
            int n = ct * 16 + low;
            float v = (n < 128) ? e1W1[k * 128 + n] : e2W1[k * 128 + (n - 128)];
            packE[((ct * 2 + kt) * 64 + lane) * 8 + j] = (__bf16)v;
        }
    } else if (bid < 160) {                           // node1 / node2 B pack [256 x 128]
        bool is1 = bid < 96;
        int tile = bid - (is1 ? 32 : 96);
        const float* nW  = is1 ? n1W  : n2W;
        const float* eW2 = is1 ? e1W2 : e2W2;
        __bf16* dst = is1 ? packN1 : packN2;
        int ct = tile >> 3, kt = tile & 7;
        for (int j = 0; j < 8; ++j) {
            int k = kt * 32 + quad * 8 + j;
            int n = ct * 16 + low;
            float v;
            if (k < 128) {
                v = nW[k * 128 + n];
            } else {
                int i = k - 128;
                float acc = 0.f;
                for (int k2 = 0; k2 < 128; ++k2)
                    acc += eW2[i * 128 + k2] * nW[(128 + k2) * 128 + n];
                v = acc;
            }
            dst[((ct * 8 + kt) * 64 + lane) * 8 + j] = (__bf16)v;
        }
    } else if (bid < 192) {                           // head B pack [128 x 128]
        int tile = bid - 160;
        int ct = tile >> 2, kt = tile & 3;
        for (int j = 0; j < 8; ++j) {
            int k = kt * 32 + quad * 8 + j;
            int n = ct * 16 + low;
            float v = (n < 64) ? muW[k * 64 + n] : lvW[k * 64 + (n - 64)];
            packH[((ct * 4 + kt) * 64 + lane) * 8 + j] = (__bf16)v;
        }
    } else if (bid == 192 || bid == 193) {            // c1 / c2
        const float* nW  = (bid == 192) ? n1W  : n2W;
        const float* nb  = (bid == 192) ? n1b  : n2b;
        const float* eb2 = (bid == 192) ? e1b2 : e2b2;
        float* dst = (bid == 192) ? c1 : c2;
        for (int rep = 0; rep < 2; ++rep) {
            int j = lane + rep * 64;
            float acc = nb[j];
            for (int k = 0; k < 128; ++k)
                acc += eb2[k] * nW[(128 + k) * 128 + j];
            dst[j] = acc;
        }
    } else {                                          // biases
        for (int rep = 0; rep < 4; ++rep) {
            int j = lane + rep * 64;
            ebias[j] = (j < 128) ? e1b1[j] : e2b1[j - 128];
        }
        for (int rep = 0; rep < 2; ++rep) {
            int j = lane + rep * 64;
            hbias[j] = (j < 64) ? mub[j] : lvb[j - 64];
        }
    }
}

// --------------------------- counting sort by dst ---------------------------
__global__ void hist_kernel(const int* __restrict__ dstp, int* __restrict__ deg) {
    int e = blockIdx.x * 256 + threadIdx.x;
    if (e < N_EDGES) atomicAdd(&deg[dstp[e]], 1);
}

__global__ void scan_a(const int* __restrict__ deg, int* __restrict__ offs,
                       int* __restrict__ tileSum, float* __restrict__ degf) {
    __shared__ int s[512];
    int t = threadIdx.x, i = blockIdx.x * 512 + t;
    int v = (i < N_NODES) ? deg[i] : 0;
    if (i < N_NODES) degf[i] = (float)v;       // folded from old scan_c
    s[t] = v; __syncthreads();
    for (int off = 1; off < 512; off <<= 1) {
        int x = (t >= off) ? s[t - off] : 0;
        __syncthreads();
        s[t] += x;
        __syncthreads();
    }
    if (i < N_NODES) offs[i] = s[t] - v;       // exclusive within tile
    if (t == 511) tileSum[blockIdx.x] = s[511];
}

__global__ void scan_b(const int* __restrict__ tileSum, int* __restrict__ tileOff) {
    __shared__ int s[128];
    int t = threadIdx.x;
    int v = (t < NTILES) ? tileSum[t] : 0;
    s[t] = v; __syncthreads();
    for (int off = 1; off < 128; off <<= 1) {
        int x = (t >= off) ? s[t - off] : 0;
        __syncthreads();
        s[t] += x;
        __syncthreads();
    }
    if (t < NTILES) tileOff[t] = s[t] - v;
}

__global__ void scatter_kernel(const int* __restrict__ dstp, const int* __restrict__ offs,
                               const int* __restrict__ tileOff,
                               int* __restrict__ cursor, int* __restrict__ sorted,
                               int* __restrict__ sdst) {
    int e = blockIdx.x * 256 + threadIdx.x;
    if (e < N_EDGES) {
        int d = dstp[e];
        int p = offs[d] + tileOff[d >> 9] + atomicAdd(&cursor[d], 1);
        sorted[p] = e;
        sdst[p] = d;
    }
}

// ---------------------------------------------------------------------------
// Edge kernel v10: v7's proven register layout + single-barrier pipeline.
//  * As double-buffered (dedicated, swizzled stride-64): the only cross-wave
//    LDS object. One __syncthreads per iteration serializes both "writes of
//    As[next] visible" and "reads of As[cur] done before overwrite in it+2"
//    (ping-pong gives the second a full-iteration slack). The prefetch gather
//    issued at iteration top drains at that single end-of-iter barrier with
//    GEMM1+epilogue+GEMM2 (~1000 cy) in flight — v7 drained it at barrier C
//    ~300 cy after issue.
//  * Run metadata fully in registers (v9b-verified: ballot + popcll selector
//    + ds_permute run->dst table). No LDS run arrays, no w0-only phase.
//  * Registers: v7 layout — full C1[4][4] (64 AGPR), immediate atomics, no
//    deferred state, __launch_bounds__(256, 3). v8 measured 84+64=148 <= 168,
//    no spills; v10's live set is smaller (run arrays gone).
//  * LDS = 2*8192 (As) + 32768 (Lb) = 49152 B -> 3 blocks/CU (= register cap).
//  * Swizzle byte ^= (row&7)<<4 on both As and Lb (v9b-verified mapping;
//    halves bank conflicts vs stride-72).
// ---------------------------------------------------------------------------
__global__ __launch_bounds__(256, 3) void edge_kernel(
    const float* __restrict__ edge_attr,
    const int* __restrict__ sorted, const int* __restrict__ sdst,
    const __bf16* __restrict__ packE,
    const float* __restrict__ ebias, float* __restrict__ S)
{
    __shared__ alignas(16) __bf16 Asd[2][64 * 64];     // 16384 B, swizzled
    __shared__ alignas(16) __bf16 Lball[4][64 * 64];   // 32768 B, per-wave slices

    int tid = threadIdx.x;
    int w = tid >> 6, lane = tid & 63;
    int quad = lane >> 4, low = lane & 15;
    int r = tid >> 2, c0 = (tid & 3) * 16;

    auto swz = [](int row, int cb) { return row * 128 + (cb ^ ((row & 7) << 4)); };

    // hoist weight fragments + bias into registers
    bf16x8 bfragE[2][4];
    #pragma unroll
    for (int kt = 0; kt < 2; ++kt)
        #pragma unroll
        for (int ct = 0; ct < 4; ++ct)
            bfragE[kt][ct] = *reinterpret_cast<const bf16x8*>(
                packE + (((w * 4 + ct) * 2 + kt) * 64 + lane) * 8);
    float bias_c[4];
    #pragma unroll
    for (int ct = 0; ct < 4; ++ct) bias_c[ct] = ebias[w * 64 + ct * 16 + low];

    char* LbB = reinterpret_cast<char*>(&Lball[w][0]);

    constexpr int STRIDE = NB_EDGE * 64;
    int e0 = blockIdx.x * 64;

    // stage helper: thread r holds row r, element cols c0..c0+15 of the tile
    auto stage = [&](int buf, const float4& a0, const float4& a1,
                     const float4& a2, const float4& a3) {
        char* AsB = reinterpret_cast<char*>(&Asd[buf][0]);
        bf16x8 v0, v1;
        v0[0]=(__bf16)a0.x; v0[1]=(__bf16)a0.y; v0[2]=(__bf16)a0.z; v0[3]=(__bf16)a0.w;
        v0[4]=(__bf16)a1.x; v0[5]=(__bf16)a1.y; v0[6]=(__bf16)a1.z; v0[7]=(__bf16)a1.w;
        v1[0]=(__bf16)a2.x; v1[1]=(__bf16)a2.y; v1[2]=(__bf16)a2.z; v1[3]=(__bf16)a2.w;
        v1[4]=(__bf16)a3.x; v1[5]=(__bf16)a3.y; v1[6]=(__bf16)a3.z; v1[7]=(__bf16)a3.w;
        *reinterpret_cast<bf16x8*>(AsB + swz(r, c0 * 2))      = v0;
        *reinterpret_cast<bf16x8*>(AsB + swz(r, c0 * 2 + 16)) = v1;
    };

    // ---- prologue ----
    float4 f0, f1, f2, f3;
    int md_c, md_n, md_n2, ei_n2;
    {
        int ei = sorted[e0 + r];
        md_c = sdst[e0 + lane];
        const float4* ap = reinterpret_cast<const float4*>(edge_attr + (size_t)ei * 64 + c0);
        f0 = ap[0]; f1 = ap[1]; f2 = ap[2]; f3 = ap[3];
    }
    stage(0, f0, f1, f2, f3);                          // As[0] = tile 0
    {
        int ei1 = sorted[e0 + STRIDE + r];
        md_n = sdst[e0 + STRIDE + lane];
        const float4* ap = reinterpret_cast<const float4*>(edge_attr + (size_t)ei1 * 64 + c0);
        f0 = ap[0]; f1 = ap[1]; f2 = ap[2]; f3 = ap[3]; // f* = tile 1 attr
    }
    ei_n2 = sorted[e0 + 2 * STRIDE + r];
    md_n2 = sdst[e0 + 2 * STRIDE + lane];
    __syncthreads();                                   // As[0] visible
    int cur = 0;

    #pragma unroll 1
    for (int it = 0; it < 4; ++it) {
        // ---- stage tile it+1 into As[cur^1] from registers ----
        if (it < 3) stage(cur ^ 1, f0, f1, f2, f3);

        // ---- prefetch: tile it+2 attr, tile it+3 indices ----
        float4 g0{}, g1{}, g2{}, g3{};
        if (it < 2) {
            const float4* gp = reinterpret_cast<const float4*>(
                edge_attr + (size_t)ei_n2 * 64 + c0);
            g0 = gp[0]; g1 = gp[1]; g2 = gp[2]; g3 = gp[3];
        }
        int ei_n3 = 0, md_n3 = 0;
        if (it < 1) {
            ei_n3 = sorted[e0 + 3 * STRIDE + r];
            md_n3 = sdst[e0 + 3 * STRIDE + lane];
        }

        // ---- run structure for tile it, in registers (v9b-verified) ----
        int dp = __shfl_up(md_c, 1);
        bool flag = (lane > 0) && (md_c != dp);
        unsigned long long mask = __ballot(flag);
        int nruns = __popcll(mask) + 1;
        int rid = __popcll(mask & ((1ull << lane) - 1ull)) + (flag ? 1 : 0);
        int vdst = __builtin_amdgcn_ds_permute(rid << 2, md_c);  // lane j = dst of run j

        // ---- GEMM1: C1[rt][ct] from As[cur] ----
        const char* AsB = reinterpret_cast<const char*>(&Asd[cur][0]);
        f32x4 C1[4][4] = {};
        #pragma unroll
        for (int kt = 0; kt < 2; ++kt)
            #pragma unroll
            for (int rt = 0; rt < 4; ++rt) {
                bf16x8 a = *reinterpret_cast<const bf16x8*>(
                    AsB + swz(rt * 16 + low, kt * 64 + quad * 16));
                #pragma unroll
                for (int ct = 0; ct < 4; ++ct)
                    C1[rt][ct] = __builtin_amdgcn_mfma_f32_16x16x32_bf16(
                        a, bfragE[kt][ct], C1[rt][ct], 0, 0, 0);
            }

        // ---- epilogue: bias + leaky -> wave-local Lb (col-major, swizzled) ----
        #pragma unroll
        for (int rt = 0; rt < 4; ++rt)
            #pragma unroll
            for (int ct = 0; ct < 4; ++ct) {
                bf16x4 v;
                #pragma unroll
                for (int rr = 0; rr < 4; ++rr)
                    v[rr] = (__bf16)leaky(C1[rt][ct][rr] + bias_c[ct]);
                *reinterpret_cast<bf16x4*>(
                    LbB + swz(ct * 16 + low, rt * 32 + quad * 8)) = v;
            }

        // ---- GEMM2: S_part = R @ L, selector from mask; immediate atomics ----
        for (int rt2 = 0; rt2 * 16 < nruns; ++rt2) {
            int target = rt2 * 16 + low;
            f32x4 C2[4] = {};
            #pragma unroll
            for (int kt = 0; kt < 2; ++kt) {
                int bsh = 63 - kt * 32 - quad * 8;
                bf16x8 a;
                #pragma unroll
                for (int j = 0; j < 8; ++j) {
                    int ride = __popcll(mask << (bsh - j));   // run id of edge kt*32+quad*8+j
                    a[j] = (ride == target) ? (__bf16)1.0f : (__bf16)0.0f;
                }
                #pragma unroll
                for (int ct = 0; ct < 4; ++ct) {
                    bf16x8 b = *reinterpret_cast<const bf16x8*>(
                        LbB + swz(ct * 16 + low, kt * 64 + quad * 16));
                    C2[ct] = __builtin_amdgcn_mfma_f32_16x16x32_bf16(a, b, C2[ct], 0, 0, 0);
                }
            }
            int node4[4];
            #pragma unroll
            for (int rr = 0; rr < 4; ++rr)
                node4[rr] = __shfl(vdst, rt2 * 16 + quad * 4 + rr);
            #pragma unroll
            for (int ct = 0; ct < 4; ++ct) {
                int col = w * 64 + ct * 16 + low;
                #pragma unroll
                for (int rr = 0; rr < 4; ++rr) {
                    int run = rt2 * 16 + quad * 4 + rr;
                    if (run < nruns && (unsigned)node4[rr] < (unsigned)N_NODES)
                        unsafeAtomicAdd(&S[(size_t)node4[rr] * 256 + col], C2[ct][rr]);
                }
            }
        }

        if (it < 3) __syncthreads();   // single drain point per iteration

        // ---- rotate pipeline registers ----
        f0 = g0; f1 = g1; f2 = g2; f3 = g3;
        md_c = md_n; md_n = md_n2; md_n2 = md_n3; ei_n2 = ei_n3;
        cur ^= 1;
    }
}

// ---------------------------------------------------------------------------
// Fused node pipeline: conv1 -> conv2 -> heads in ONE kernel.
// Row-local: h[r]=leaky(deg*x[r]@Wt1+deg*c1 + S1[r]@M1); same for g; out=g@[muW|lvW].
// h,g hand off through wave-local LDS (row-major bf16, stride 152).
// h is stored pre-scaled by deg (folds conv2's row scaling).
// ---------------------------------------------------------------------------
__global__ __launch_bounds__(256) void node_fused(
    const float* __restrict__ x, const float* __restrict__ S,
    const float* __restrict__ degf,
    const __bf16* __restrict__ packN1, const __bf16* __restrict__ packN2,
    const __bf16* __restrict__ packH,
    const float* __restrict__ c1, const float* __restrict__ c2,
    const float* __restrict__ hbias,
    float* __restrict__ out)
{
    constexpr int HS = 152;                        // row stride (elements), 304 B
    __shared__ __bf16 Hs[4][16 * HS];              // 19456 B
    int w = threadIdx.x >> 6, lane = threadIdx.x & 63;
    int quad = lane >> 4, low = lane & 15;
    int rb = blockIdx.x * 64 + w * 16;

    int arow = rb + low;
    if (arow >= N_NODES) arow = N_NODES - 1;
    float ds = degf[arow];
    const float* xrow = x + (size_t)arow * 128;
    const float* Srow = S + (size_t)arow * 256;

    float deg4[4];
    #pragma unroll
    for (int rr = 0; rr < 4; ++rr) {
        int row = rb + quad * 4 + rr;
        deg4[rr] = degf[row < N_NODES ? row : N_NODES - 1];
    }

    __bf16* Hw = Hs[w];

    // ---- conv1: C = [deg*x | S1] @ packN1 ----
    f32x4 C[8] = {};
    #pragma unroll
    for (int kt = 0; kt < 8; ++kt) {
        const float* base = (kt < 4) ? (xrow + kt * 32 + quad * 8)
                                     : (Srow + (kt - 4) * 32 + quad * 8);
        float4 p0 = *reinterpret_cast<const float4*>(base);
        float4 p1 = *reinterpret_cast<const float4*>(base + 4);
        float m = (kt < 4) ? ds : 1.f;
        bf16x8 a;
        a[0]=(__bf16)(p0.x*m); a[1]=(__bf16)(p0.y*m); a[2]=(__bf16)(p0.z*m); a[3]=(__bf16)(p0.w*m);
        a[4]=(__bf16)(p1.x*m); a[5]=(__bf16)(p1.y*m); a[6]=(__bf16)(p1.z*m); a[7]=(__bf16)(p1.w*m);
        #pragma unroll
        for (int ct = 0; ct < 8; ++ct) {
            bf16x8 b = *reinterpret_cast<const bf16x8*>(packN1 + ((ct * 8 + kt) * 64 + lane) * 8);
            C[ct] = __builtin_amdgcn_mfma_f32_16x16x32_bf16(a, b, C[ct], 0, 0, 0);
        }
    }
    // epilogue: store deg*h (pre-scaled for conv2) row-major bf16
    #pragma unroll
    for (int ct = 0; ct < 8; ++ct) {
        int col = ct * 16 + low;
        float cb = c1[col];
        #pragma unroll
        for (int rr = 0; rr < 4; ++rr) {
            float v = leaky(C[ct][rr] + deg4[rr] * cb);
            Hw[(quad * 4 + rr) * HS + col] = (__bf16)(v * deg4[rr]);
        }
    }

    // ---- conv2: C2 = [deg*h | S2] @ packN2 ----
    f32x4 C2[8] = {};
    #pragma unroll
    for (int kt = 0; kt < 8; ++kt) {
        bf16x8 a;
        if (kt < 4) {
            a = *reinterpret_cast<const bf16x8*>(&Hw[low * HS + kt * 32 + quad * 8]);
        } else {
            const float* base = Srow + 128 + (kt - 4) * 32 + quad * 8;
            float4 p0 = *reinterpret_cast<const float4*>(base);
            float4 p1 = *reinterpret_cast<const float4*>(base + 4);
            a[0]=(__bf16)p0.x; a[1]=(__bf16)p0.y; a[2]=(__bf16)p0.z; a[3]=(__bf16)p0.w;
            a[4]=(__bf16)p1.x; a[5]=(__bf16)p1.y; a[6]=(__bf16)p1.z; a[7]=(__bf16)p1.w;
        }
        #pragma unroll
        for (int ct = 0; ct < 8; ++ct) {
            bf16x8 b = *reinterpret_cast<const bf16x8*>(packN2 + ((ct * 8 + kt) * 64 + lane) * 8);
            C2[ct] = __builtin_amdgcn_mfma_f32_16x16x32_bf16(a, b, C2[ct], 0, 0, 0);
        }
    }
    // epilogue: store g (unscaled) over the same LDS
    #pragma unroll
    for (int ct = 0; ct < 8; ++ct) {
        int col = ct * 16 + low;
        float cb = c2[col];
        #pragma unroll
        for (int rr = 0; rr < 4; ++rr) {
            float v = leaky(C2[ct][rr] + deg4[rr] * cb);
            Hw[(quad * 4 + rr) * HS + col] = (__bf16)v;
        }
    }

    // ---- heads: C3 = g @ [muW|lvW] ----
    f32x4 C3[8] = {};
    #pragma unroll
    for (int kt = 0; kt < 4; ++kt) {
        bf16x8 a = *reinterpret_cast<const bf16x8*>(&Hw[low * HS + kt * 32 + quad * 8]);
        #pragma unroll
        for (int ct = 0; ct < 8; ++ct) {
            bf16x8 b = *reinterpret_cast<const bf16x8*>(packH + ((ct * 4 + kt) * 64 + lane) * 8);
            C3[ct] = __builtin_amdgcn_mfma_f32_16x16x32_bf16(a, b, C3[ct], 0, 0, 0);
        }
    }
    #pragma unroll
    for (int ct = 0; ct < 8; ++ct) {
        int col = ct * 16 + low;
        float hb = hbias[col];
        #pragma unroll
        for (int rr = 0; rr < 4; ++rr) {
            int row = rb + quad * 4 + rr;
            if (row >= N_NODES) continue;
            float v = C3[ct][rr] + hb;
            if (col < 64) out[(size_t)row * 64 + col] = v;
            else          out[(size_t)N_NODES * 64 + (size_t)row * 64 + (col - 64)] = v;
        }
    }
}

// ---------------------------------------------------------------------------
extern "C" void kernel_launch(void* const* d_in, const int* in_sizes, int n_in,
                              void* d_out, int out_size, void* d_ws, size_t ws_size,
                              hipStream_t stream)
{
    const float* x     = (const float*)d_in[0];
    const int*   eidx  = (const int*)  d_in[1];
    const float* eattr = (const float*)d_in[2];
    const float* e1W1 = (const float*)d_in[3];
    const float* e1b1 = (const float*)d_in[4];
    const float* e1W2 = (const float*)d_in[5];
    const float* e1b2 = (const float*)d_in[6];
    const float* n1W  = (const float*)d_in[7];
    const float* n1b  = (const float*)d_in[8];
    const float* e2W1 = (const float*)d_in[9];
    const float* e2b1 = (const float*)d_in[10];
    const float* e2W2 = (const float*)d_in[11];
    const float* e2b2 = (const float*)d_in[12];
    const float* n2W  = (const float*)d_in[13];
    const float* n2b  = (const float*)d_in[14];
    const float* muW  = (const float*)d_in[15];
    const float* mub  = (const float*)d_in[16];
    const float* lvW  = (const float*)d_in[17];
    const float* lvb  = (const float*)d_in[18];

    const int* dstp = eidx + N_EDGES;   // edge_index row 1

    char* ws = (char*)d_ws;
    size_t off = 0;
    auto alloc = [&](size_t bytes) -> void* {
        void* p = ws + off;
        off = (off + bytes + 1023) & ~(size_t)1023;
        return p;
    };
    float* S       = (float*)alloc((size_t)N_NODES * 256 * 4);   // [N][256] S1|S2
    float* h       = (float*)alloc((size_t)N_NODES * 128 * 4);   // unused (layout keep)
    float* g       = (float*)alloc((size_t)N_NODES * 128 * 4);   // backs sdst
    int*   deg     = (int*)  alloc((size_t)N_NODES * 4);
    int*   cursor  = (int*)  alloc((size_t)N_NODES * 4);
    int*   offs    = (int*)  alloc((size_t)N_NODES * 4);
    float* degf    = (float*)alloc((size_t)N_NODES * 4);
    int*   sorted  = (int*)  alloc((size_t)N_EDGES * 4);
    int*   tileSum = (int*)  alloc(NTILES * 4);
    int*   tileOff = (int*)  alloc(NTILES * 4);
    __bf16* packE  = (__bf16*)alloc(32 * 64 * 8 * 2);
    __bf16* packN1 = (__bf16*)alloc(64 * 64 * 8 * 2);
    __bf16* packN2 = (__bf16*)alloc(64 * 64 * 8 * 2);
    __bf16* packH  = (__bf16*)alloc(32 * 64 * 8 * 2);
    float* ebias   = (float*)alloc(256 * 4);
    float* c1      = (float*)alloc(128 * 4);
    float* c2      = (float*)alloc(128 * 4);
    float* hbias   = (float*)alloc(128 * 4);
    (void)ws_size; (void)in_sizes; (void)n_in; (void)out_size; (void)h;

    int* sdst = (int*)g;   // g region is free scratch (node pipeline fused)

    hipMemsetAsync(S, 0, (size_t)N_NODES * 256 * 4, stream);
    // deg + cursor are adjacent 1024-padded allocations -> one memset
    hipMemsetAsync(deg, 0, 2 * (((size_t)N_NODES * 4 + 1023) & ~(size_t)1023), stream);

    prep_kernel<<<195, 64, 0, stream>>>(e1W1, e1b1, e1W2, e1b2, n1W, n1b,
                                        e2W1, e2b1, e2W2, e2b2, n2W, n2b,
                                        muW, mub, lvW, lvb,
                                        packE, packN1, packN2, packH,
                                        ebias, c1, c2, hbias);

    hist_kernel<<<N_EDGES / 256, 256, 0, stream>>>(dstp, deg);
    scan_a<<<NTILES, 512, 0, stream>>>(deg, offs, tileSum, degf);
    scan_b<<<1, 128, 0, stream>>>(tileSum, tileOff);
    scatter_kernel<<<N_EDGES / 256, 256, 0, stream>>>(dstp, offs, tileOff, cursor, sorted, sdst);

    edge_kernel<<<NB_EDGE, 256, 0, stream>>>(eattr, sorted, sdst, packE, ebias, S);

    node_fused<<<(N_NODES + 63) / 64, 256, 0, stream>>>(
        x, S, degf, packN1, packN2, packH, c1, c2, hbias, (float*)d_out);
}

// Round 5
// 460.036 us; speedup vs baseline: 1.3682x; 1.1466x over previous
//
#include <hip/hip_runtime.h>

typedef __bf16 bf16x4 __attribute__((ext_vector_type(4)));
typedef __bf16 bf16x8 __attribute__((ext_vector_type(8)));
typedef float  f32x4  __attribute__((ext_vector_type(4)));

constexpr int N_NODES = 50000;
constexpr int N_EDGES = 640000;
constexpr int NTILES  = 98;     // ceil(50000/512)
constexpr int NB_EDGE = 2500;   // edge blocks; 10000 tiles / 2500 = exactly 4 tiles each

__device__ __forceinline__ float leaky(float v) { return v >= 0.f ? v : 0.15f * v; }

// ---------------------------------------------------------------------------
// Prep: pack all weight matrices into MFMA B-fragment order (bf16) and fold
// the linear algebra:  M = eW2 @ nW[128:],  c = nb + eb2 @ nW[128:]
// ---------------------------------------------------------------------------
__global__ void prep_kernel(
    const float* __restrict__ e1W1, const float* __restrict__ e1b1,
    const float* __restrict__ e1W2, const float* __restrict__ e1b2,
    const float* __restrict__ n1W,  const float* __restrict__ n1b,
    const float* __restrict__ e2W1, const float* __restrict__ e2b1,
    const float* __restrict__ e2W2, const float* __restrict__ e2b2,
    const float* __restrict__ n2W,  const float* __restrict__ n2b,
    const float* __restrict__ muW,  const float* __restrict__ mub,
    const float* __restrict__ lvW,  const float* __restrict__ lvb,
    __bf16* __restrict__ packE, __bf16* __restrict__ packN1,
    __bf16* __restrict__ packN2, __bf16* __restrict__ packH,
    float* __restrict__ ebias, float* __restrict__ c1, float* __restrict__ c2,
    float* __restrict__ hbias)
{
    int bid = blockIdx.x;
    int lane = threadIdx.x;          // 64 threads
    int quad = lane >> 4, low = lane & 15;

    if (bid < 32) {                                   // edge B pack [64 x 256]
        int ct = bid >> 1, kt = bid & 1;
        for (int j = 0; j < 8; ++j) {
            int k = kt * 32 + quad * 8 + j;
            int n = ct * 16 + low;
            float v = (n < 128) ? e1W1[k * 128 + n] : e2W1[k * 128 + (n - 128)];
            packE[((ct * 2 + kt) * 64 + lane) * 8 + j] = (__bf16)v;
        }
    } else if (bid < 160) {                           // node1 / node2 B pack [256 x 128]
        bool is1 = bid < 96;
        int tile = bid - (is1 ? 32 : 96);
        const float* nW  = is1 ? n1W  : n2W;
        const float* eW2 = is1 ? e1W2 : e2W2;
        __bf16* dst = is1 ? packN1 : packN2;
        int ct = tile >> 3, kt = tile & 7;
        for (int j = 0; j < 8; ++j) {
            int k = kt * 32 + quad * 8 + j;
            int n = ct * 16 + low;
            float v;
            if (k < 128) {
                v = nW[k * 128 + n];
            } else {
                int i = k - 128;
                float acc = 0.f;
                for (int k2 = 0; k2 < 128; ++k2)
                    acc += eW2[i * 128 + k2] * nW[(128 + k2) * 128 + n];
                v = acc;
            }
            dst[((ct * 8 + kt) * 64 + lane) * 8 + j] = (__bf16)v;
        }
    } else if (bid < 192) {                           // head B pack [128 x 128]
        int tile = bid - 160;
        int ct = tile >> 2, kt = tile & 3;
        for (int j = 0; j < 8; ++j) {
            int k = kt * 32 + quad * 8 + j;
            int n = ct * 16 + low;
            float v = (n < 64) ? muW[k * 64 + n] : lvW[k * 64 + (n - 64)];
            packH[((ct * 4 + kt) * 64 + lane) * 8 + j] = (__bf16)v;
        }
    } else if (bid == 192 || bid == 193) {            // c1 / c2
        const float* nW  = (bid == 192) ? n1W  : n2W;
        const float* nb  = (bid == 192) ? n1b  : n2b;
        const float* eb2 = (bid == 192) ? e1b2 : e2b2;
        float* dst = (bid == 192) ? c1 : c2;
        for (int rep = 0; rep < 2; ++rep) {
            int j = lane + rep * 64;
            float acc = nb[j];
            for (int k = 0; k < 128; ++k)
                acc += eb2[k] * nW[(128 + k) * 128 + j];
            dst[j] = acc;
        }
    } else {                                          // biases
        for (int rep = 0; rep < 4; ++rep) {
            int j = lane + rep * 64;
            ebias[j] = (j < 128) ? e1b1[j] : e2b1[j - 128];
        }
        for (int rep = 0; rep < 2; ++rep) {
            int j = lane + rep * 64;
            hbias[j] = (j < 64) ? mub[j] : lvb[j - 64];
        }
    }
}

// --------------------------- counting sort by dst ---------------------------
__global__ void hist_kernel(const int* __restrict__ dstp, int* __restrict__ deg) {
    int e = blockIdx.x * 256 + threadIdx.x;
    if (e < N_EDGES) atomicAdd(&deg[dstp[e]], 1);
}

__global__ void scan_a(const int* __restrict__ deg, int* __restrict__ offs,
                       int* __restrict__ tileSum, float* __restrict__ degf) {
    __shared__ int s[512];
    int t = threadIdx.x, i = blockIdx.x * 512 + t;
    int v = (i < N_NODES) ? deg[i] : 0;
    if (i < N_NODES) degf[i] = (float)v;       // folded from old scan_c
    s[t] = v; __syncthreads();
    for (int off = 1; off < 512; off <<= 1) {
        int x = (t >= off) ? s[t - off] : 0;
        __syncthreads();
        s[t] += x;
        __syncthreads();
    }
    if (i < N_NODES) offs[i] = s[t] - v;       // exclusive within tile
    if (t == 511) tileSum[blockIdx.x] = s[511];
}

__global__ void scan_b(const int* __restrict__ tileSum, int* __restrict__ tileOff) {
    __shared__ int s[128];
    int t = threadIdx.x;
    int v = (t < NTILES) ? tileSum[t] : 0;
    s[t] = v; __syncthreads();
    for (int off = 1; off < 128; off <<= 1) {
        int x = (t >= off) ? s[t - off] : 0;
        __syncthreads();
        s[t] += x;
        __syncthreads();
    }
    if (t < NTILES) tileOff[t] = s[t] - v;
}

__global__ void scatter_kernel(const int* __restrict__ dstp, const int* __restrict__ offs,
                               const int* __restrict__ tileOff,
                               int* __restrict__ cursor, int* __restrict__ sorted,
                               int* __restrict__ sdst) {
    int e = blockIdx.x * 256 + threadIdx.x;
    if (e < N_EDGES) {
        int d = dstp[e];
        int p = offs[d] + tileOff[d >> 9] + atomicAdd(&cursor[d], 1);
        sorted[p] = e;
        sdst[p] = d;
    }
}

// ---------------------------------------------------------------------------
// Edge kernel v11 = round-0 v7 EXACTLY (3 barriers, wave-0 LDS run metadata,
// As aliased onto wave-0's Lb slice, immediate atomics, (256,3)) with ONE
// verified substitution: the stride-72 tile layout is replaced by stride-64 +
// XOR swizzle byte ^= (row&7)<<4 (correctness-proven in two passing runs;
// halves SQ_LDS_BANK_CONFLICT 5.12M -> 2.56M). Zero register-pressure impact;
// all pipeline structure, barriers, and register layout are byte-identical
// to the 452 µs configuration. LDS 37.4 KB -> ~33 KB.
// v8/v9/v10 lesson: this kernel sits at the spill cliff — structural changes
// (dealias, dbuf, deferred atomics, reg run-metadata) all spilled or
// serialized; do not touch the structure.
// ---------------------------------------------------------------------------
__global__ __launch_bounds__(256, 3) void edge_kernel(
    const float* __restrict__ edge_attr,
    const int* __restrict__ sorted, const int* __restrict__ sdst,
    const __bf16* __restrict__ packE,
    const float* __restrict__ ebias, float* __restrict__ S)
{
    __shared__ alignas(16) __bf16 Lball[4 * 64 * 64];  // 32768 B; slice 0 doubles as As
    __shared__ alignas(8) unsigned char runof_s[64];
    __shared__ int rundst_s[64];
    __shared__ int nruns_s;

    int tid = threadIdx.x;
    int w = tid >> 6, lane = tid & 63;
    int quad = lane >> 4, low = lane & 15;
    int r = tid >> 2, c0 = (tid & 3) * 16;

    // swizzled byte offset within a 64-row x 128-byte tile
    auto swz = [](int row, int cb) { return row * 128 + (cb ^ ((row & 7) << 4)); };

    // hoist weight fragments + bias into registers for all 4 tiles
    bf16x8 bfragE[2][4];
    #pragma unroll
    for (int kt = 0; kt < 2; ++kt)
        #pragma unroll
        for (int ct = 0; ct < 4; ++ct)
            bfragE[kt][ct] = *reinterpret_cast<const bf16x8*>(
                packE + (((w * 4 + ct) * 2 + kt) * 64 + lane) * 8);
    float bias_c[4];
    #pragma unroll
    for (int ct = 0; ct < 4; ++ct) bias_c[ct] = ebias[w * 64 + ct * 16 + low];

    char* AsB = reinterpret_cast<char*>(Lball);            // alias: wave-0's L slice
    char* LbB = reinterpret_cast<char*>(&Lball[w * 4096]); // wave-local L slice

    constexpr int STRIDE = NB_EDGE * 64;
    int e0 = blockIdx.x * 64;

    // ---- prologue: tile 0 attr + dst, tile 1 indices ----
    float4 f0, f1, f2, f3;
    int md_c, ei_n, md_n;
    {
        int ei = sorted[e0 + r];
        md_c = sdst[e0 + lane];
        const float4* ap = reinterpret_cast<const float4*>(edge_attr + (size_t)ei * 64 + c0);
        f0 = ap[0]; f1 = ap[1]; f2 = ap[2]; f3 = ap[3];
    }
    ei_n = sorted[e0 + STRIDE + r];
    md_n = sdst[e0 + STRIDE + lane];

    #pragma unroll 1
    for (int it = 0; it < 4; ++it) {
        // ---- stage As from registers (bf16, swizzled stride-64) ----
        {
            bf16x8 v0, v1;
            v0[0]=(__bf16)f0.x; v0[1]=(__bf16)f0.y; v0[2]=(__bf16)f0.z; v0[3]=(__bf16)f0.w;
            v0[4]=(__bf16)f1.x; v0[5]=(__bf16)f1.y; v0[6]=(__bf16)f1.z; v0[7]=(__bf16)f1.w;
            v1[0]=(__bf16)f2.x; v1[1]=(__bf16)f2.y; v1[2]=(__bf16)f2.z; v1[3]=(__bf16)f2.w;
            v1[4]=(__bf16)f3.x; v1[5]=(__bf16)f3.y; v1[6]=(__bf16)f3.z; v1[7]=(__bf16)f3.w;
            *reinterpret_cast<bf16x8*>(AsB + swz(r, c0 * 2))      = v0;
            *reinterpret_cast<bf16x8*>(AsB + swz(r, c0 * 2 + 16)) = v1;
        }

        // ---- run structure (wave 0) ----
        if (w == 0) {
            rundst_s[lane] = md_c;                     // defensive init: valid ids
            int dp = __shfl_up(md_c, 1);
            bool flag = (lane > 0) && (md_c != dp);
            unsigned long long mask = __ballot(flag);
            int rid = __popcll(mask & ((1ull << lane) - 1ull)) + (flag ? 1 : 0);
            runof_s[lane] = (unsigned char)rid;
            if (flag || lane == 0) rundst_s[rid] = md_c;
            if (lane == 0) nruns_s = __popcll(mask) + 1;
        }
        __syncthreads();                               // B: As + run info ready

        // ---- prefetch: tile it+1 attr, tile it+2 indices ----
        float4 g0{}, g1{}, g2{}, g3{};
        if (it < 3) {
            const float4* gp = reinterpret_cast<const float4*>(
                edge_attr + (size_t)ei_n * 64 + c0);
            g0 = gp[0]; g1 = gp[1]; g2 = gp[2]; g3 = gp[3];
        }
        int ei_nn = 0, md_nn = 0;
        if (it < 2) {
            int eo = e0 + (it + 2) * STRIDE;
            ei_nn = sorted[eo + r];
            md_nn = sdst[eo + lane];
        }

        // ---- GEMM1: C1[rt][ct], wave cols w*64 + ct*16 + low ----
        f32x4 C1[4][4] = {};
        #pragma unroll
        for (int kt = 0; kt < 2; ++kt)
            #pragma unroll
            for (int rt = 0; rt < 4; ++rt) {
                bf16x8 a = *reinterpret_cast<const bf16x8*>(
                    AsB + swz(rt * 16 + low, kt * 64 + quad * 16));
                #pragma unroll
                for (int ct = 0; ct < 4; ++ct)
                    C1[rt][ct] = __builtin_amdgcn_mfma_f32_16x16x32_bf16(
                        a, bfragE[kt][ct], C1[rt][ct], 0, 0, 0);
            }
        __syncthreads();                               // C: all As reads done

        // ---- epilogue: bias + leaky -> wave-local Lb (col-major, swizzled) ----
        #pragma unroll
        for (int rt = 0; rt < 4; ++rt)
            #pragma unroll
            for (int ct = 0; ct < 4; ++ct) {
                bf16x4 v;
                #pragma unroll
                for (int rr = 0; rr < 4; ++rr)
                    v[rr] = (__bf16)leaky(C1[rt][ct][rr] + bias_c[ct]);
                *reinterpret_cast<bf16x4*>(
                    LbB + swz(ct * 16 + low, rt * 32 + quad * 8)) = v;
            }

        // ---- GEMM2: S_part = R @ L, atomics from C-fragments ----
        int nruns = nruns_s;
        for (int rt2 = 0; rt2 * 16 < nruns; ++rt2) {
            f32x4 C2[4] = {};
            #pragma unroll
            for (int kt = 0; kt < 2; ++kt) {
                uint2 rb2 = *reinterpret_cast<const uint2*>(&runof_s[kt * 32 + quad * 8]);
                unsigned target = (unsigned)(rt2 * 16 + low);
                bf16x8 a;
                #pragma unroll
                for (int j = 0; j < 8; ++j) {
                    unsigned byte = ((j < 4 ? (rb2.x >> (8 * j)) : (rb2.y >> (8 * (j - 4)))) & 0xFFu);
                    a[j] = (byte == target) ? (__bf16)1.0f : (__bf16)0.0f;
                }
                #pragma unroll
                for (int ct = 0; ct < 4; ++ct) {
                    bf16x8 b = *reinterpret_cast<const bf16x8*>(
                        LbB + swz(ct * 16 + low, kt * 64 + quad * 16));
                    C2[ct] = __builtin_amdgcn_mfma_f32_16x16x32_bf16(a, b, C2[ct], 0, 0, 0);
                }
            }
            #pragma unroll
            for (int ct = 0; ct < 4; ++ct) {
                int col = w * 64 + ct * 16 + low;
                #pragma unroll
                for (int rr = 0; rr < 4; ++rr) {
                    int run = rt2 * 16 + quad * 4 + rr;
                    if (run < nruns) {
                        int node = rundst_s[run];
                        if ((unsigned)node < (unsigned)N_NODES)
                            unsafeAtomicAdd(&S[(size_t)node * 256 + col], C2[ct][rr]);
                    }
                }
            }
        }
        __syncthreads();                               // E: Lb reads done before next As

        // ---- rotate pipeline registers ----
        f0 = g0; f1 = g1; f2 = g2; f3 = g3;
        md_c = md_n; ei_n = ei_nn; md_n = md_nn;
    }
}

// ---------------------------------------------------------------------------
// Fused node pipeline: conv1 -> conv2 -> heads in ONE kernel.
// Row-local: h[r]=leaky(deg*x[r]@Wt1+deg*c1 + S1[r]@M1); same for g; out=g@[muW|lvW].
// h,g hand off through wave-local LDS (row-major bf16, stride 152).
// h is stored pre-scaled by deg (folds conv2's row scaling).
// ---------------------------------------------------------------------------
__global__ __launch_bounds__(256) void node_fused(
    const float* __restrict__ x, const float* __restrict__ S,
    const float* __restrict__ degf,
    const __bf16* __restrict__ packN1, const __bf16* __restrict__ packN2,
    const __bf16* __restrict__ packH,
    const float* __restrict__ c1, const float* __restrict__ c2,
    const float* __restrict__ hbias,
    float* __restrict__ out)
{
    constexpr int HS = 152;                        // row stride (elements), 304 B
    __shared__ __bf16 Hs[4][16 * HS];              // 19456 B
    int w = threadIdx.x >> 6, lane = threadIdx.x & 63;
    int quad = lane >> 4, low = lane & 15;
    int rb = blockIdx.x * 64 + w * 16;

    int arow = rb + low;
    if (arow >= N_NODES) arow = N_NODES - 1;
    float ds = degf[arow];
    const float* xrow = x + (size_t)arow * 128;
    const float* Srow = S + (size_t)arow * 256;

    float deg4[4];
    #pragma unroll
    for (int rr = 0; rr < 4; ++rr) {
        int row = rb + quad * 4 + rr;
        deg4[rr] = degf[row < N_NODES ? row : N_NODES - 1];
    }

    __bf16* Hw = Hs[w];

    // ---- conv1: C = [deg*x | S1] @ packN1 ----
    f32x4 C[8] = {};
    #pragma unroll
    for (int kt = 0; kt < 8; ++kt) {
        const float* base = (kt < 4) ? (xrow + kt * 32 + quad * 8)
                                     : (Srow + (kt - 4) * 32 + quad * 8);
        float4 p0 = *reinterpret_cast<const float4*>(base);
        float4 p1 = *reinterpret_cast<const float4*>(base + 4);
        float m = (kt < 4) ? ds : 1.f;
        bf16x8 a;
        a[0]=(__bf16)(p0.x*m); a[1]=(__bf16)(p0.y*m); a[2]=(__bf16)(p0.z*m); a[3]=(__bf16)(p0.w*m);
        a[4]=(__bf16)(p1.x*m); a[5]=(__bf16)(p1.y*m); a[6]=(__bf16)(p1.z*m); a[7]=(__bf16)(p1.w*m);
        #pragma unroll
        for (int ct = 0; ct < 8; ++ct) {
            bf16x8 b = *reinterpret_cast<const bf16x8*>(packN1 + ((ct * 8 + kt) * 64 + lane) * 8);
            C[ct] = __builtin_amdgcn_mfma_f32_16x16x32_bf16(a, b, C[ct], 0, 0, 0);
        }
    }
    // epilogue: store deg*h (pre-scaled for conv2) row-major bf16
    #pragma unroll
    for (int ct = 0; ct < 8; ++ct) {
        int col = ct * 16 + low;
        float cb = c1[col];
        #pragma unroll
        for (int rr = 0; rr < 4; ++rr) {
            float v = leaky(C[ct][rr] + deg4[rr] * cb);
            Hw[(quad * 4 + rr) * HS + col] = (__bf16)(v * deg4[rr]);
        }
    }

    // ---- conv2: C2 = [deg*h | S2] @ packN2 ----
    f32x4 C2[8] = {};
    #pragma unroll
    for (int kt = 0; kt < 8; ++kt) {
        bf16x8 a;
        if (kt < 4) {
            a = *reinterpret_cast<const bf16x8*>(&Hw[low * HS + kt * 32 + quad * 8]);
        } else {
            const float* base = Srow + 128 + (kt - 4) * 32 + quad * 8;
            float4 p0 = *reinterpret_cast<const float4*>(base);
            float4 p1 = *reinterpret_cast<const float4*>(base + 4);
            a[0]=(__bf16)p0.x; a[1]=(__bf16)p0.y; a[2]=(__bf16)p0.z; a[3]=(__bf16)p0.w;
            a[4]=(__bf16)p1.x; a[5]=(__bf16)p1.y; a[6]=(__bf16)p1.z; a[7]=(__bf16)p1.w;
        }
        #pragma unroll
        for (int ct = 0; ct < 8; ++ct) {
            bf16x8 b = *reinterpret_cast<const bf16x8*>(packN2 + ((ct * 8 + kt) * 64 + lane) * 8);
            C2[ct] = __builtin_amdgcn_mfma_f32_16x16x32_bf16(a, b, C2[ct], 0, 0, 0);
        }
    }
    // epilogue: store g (unscaled) over the same LDS
    #pragma unroll
    for (int ct = 0; ct < 8; ++ct) {
        int col = ct * 16 + low;
        float cb = c2[col];
        #pragma unroll
        for (int rr = 0; rr < 4; ++rr) {
            float v = leaky(C2[ct][rr] + deg4[rr] * cb);
            Hw[(quad * 4 + rr) * HS + col] = (__bf16)v;
        }
    }

    // ---- heads: C3 = g @ [muW|lvW] ----
    f32x4 C3[8] = {};
    #pragma unroll
    for (int kt = 0; kt < 4; ++kt) {
        bf16x8 a = *reinterpret_cast<const bf16x8*>(&Hw[low * HS + kt * 32 + quad * 8]);
        #pragma unroll
        for (int ct = 0; ct < 8; ++ct) {
            bf16x8 b = *reinterpret_cast<const bf16x8*>(packH + ((ct * 4 + kt) * 64 + lane) * 8);
            C3[ct] = __builtin_amdgcn_mfma_f32_16x16x32_bf16(a, b, C3[ct], 0, 0, 0);
        }
    }
    #pragma unroll
    for (int ct = 0; ct < 8; ++ct) {
        int col = ct * 16 + low;
        float hb = hbias[col];
        #pragma unroll
        for (int rr = 0; rr < 4; ++rr) {
            int row = rb + quad * 4 + rr;
            if (row >= N_NODES) continue;
            float v = C3[ct][rr] + hb;
            if (col < 64) out[(size_t)row * 64 + col] = v;
            else          out[(size_t)N_NODES * 64 + (size_t)row * 64 + (col - 64)] = v;
        }
    }
}

// ---------------------------------------------------------------------------
extern "C" void kernel_launch(void* const* d_in, const int* in_sizes, int n_in,
                              void* d_out, int out_size, void* d_ws, size_t ws_size,
                              hipStream_t stream)
{
    const float* x     = (const float*)d_in[0];
    const int*   eidx  = (const int*)  d_in[1];
    const float* eattr = (const float*)d_in[2];
    const float* e1W1 = (const float*)d_in[3];
    const float* e1b1 = (const float*)d_in[4];
    const float* e1W2 = (const float*)d_in[5];
    const float* e1b2 = (const float*)d_in[6];
    const float* n1W  = (const float*)d_in[7];
    const float* n1b  = (const float*)d_in[8];
    const float* e2W1 = (const float*)d_in[9];
    const float* e2b1 = (const float*)d_in[10];
    const float* e2W2 = (const float*)d_in[11];
    const float* e2b2 = (const float*)d_in[12];
    const float* n2W  = (const float*)d_in[13];
    const float* n2b  = (const float*)d_in[14];
    const float* muW  = (const float*)d_in[15];
    const float* mub  = (const float*)d_in[16];
    const float* lvW  = (const float*)d_in[17];
    const float* lvb  = (const float*)d_in[18];

    const int* dstp = eidx + N_EDGES;   // edge_index row 1

    char* ws = (char*)d_ws;
    size_t off = 0;
    auto alloc = [&](size_t bytes) -> void* {
        void* p = ws + off;
        off = (off + bytes + 1023) & ~(size_t)1023;
        return p;
    };
    float* S       = (float*)alloc((size_t)N_NODES * 256 * 4);   // [N][256] S1|S2
    float* h       = (float*)alloc((size_t)N_NODES * 128 * 4);   // unused (layout keep)
    float* g       = (float*)alloc((size_t)N_NODES * 128 * 4);   // backs sdst
    int*   deg     = (int*)  alloc((size_t)N_NODES * 4);
    int*   cursor  = (int*)  alloc((size_t)N_NODES * 4);
    int*   offs    = (int*)  alloc((size_t)N_NODES * 4);
    float* degf    = (float*)alloc((size_t)N_NODES * 4);
    int*   sorted  = (int*)  alloc((size_t)N_EDGES * 4);
    int*   tileSum = (int*)  alloc(NTILES * 4);
    int*   tileOff = (int*)  alloc(NTILES * 4);
    __bf16* packE  = (__bf16*)alloc(32 * 64 * 8 * 2);
    __bf16* packN1 = (__bf16*)alloc(64 * 64 * 8 * 2);
    __bf16* packN2 = (__bf16*)alloc(64 * 64 * 8 * 2);
    __bf16* packH  = (__bf16*)alloc(32 * 64 * 8 * 2);
    float* ebias   = (float*)alloc(256 * 4);
    float* c1      = (float*)alloc(128 * 4);
    float* c2      = (float*)alloc(128 * 4);
    float* hbias   = (float*)alloc(128 * 4);
    (void)ws_size; (void)in_sizes; (void)n_in; (void)out_size; (void)h;

    int* sdst = (int*)g;   // g region is free scratch (node pipeline fused)

    hipMemsetAsync(S, 0, (size_t)N_NODES * 256 * 4, stream);
    // deg + cursor are adjacent 1024-padded allocations -> one memset
    hipMemsetAsync(deg, 0, 2 * (((size_t)N_NODES * 4 + 1023) & ~(size_t)1023), stream);

    prep_kernel<<<195, 64, 0, stream>>>(e1W1, e1b1, e1W2, e1b2, n1W, n1b,
                                        e2W1, e2b1, e2W2, e2b2, n2W, n2b,
                                        muW, mub, lvW, lvb,
                                        packE, packN1, packN2, packH,
                                        ebias, c1, c2, hbias);

    hist_kernel<<<N_EDGES / 256, 256, 0, stream>>>(dstp, deg);
    scan_a<<<NTILES, 512, 0, stream>>>(deg, offs, tileSum, degf);
    scan_b<<<1, 128, 0, stream>>>(tileSum, tileOff);
    scatter_kernel<<<N_EDGES / 256, 256, 0, stream>>>(dstp, offs, tileOff, cursor, sorted, sdst);

    edge_kernel<<<NB_EDGE, 256, 0, stream>>>(eattr, sorted, sdst, packE, ebias, S);

    node_fused<<<(N_NODES + 63) / 64, 256, 0, stream>>>(
        x, S, degf, packN1, packN2, packH, c1, c2, hbias, (float*)d_out);
}

// Round 6
// 456.057 us; speedup vs baseline: 1.3801x; 1.0087x over previous
//
#include <hip/hip_runtime.h>

typedef __bf16 bf16x4 __attribute__((ext_vector_type(4)));
typedef __bf16 bf16x8 __attribute__((ext_vector_type(8)));
typedef float  f32x4  __attribute__((ext_vector_type(4)));

constexpr int N_NODES = 50000;
constexpr int N_EDGES = 640000;
constexpr int NTILES  = 98;     // ceil(50000/512)

__device__ __forceinline__ float leaky(float v) { return v >= 0.f ? v : 0.15f * v; }

// ---------------------------------------------------------------------------
// Prep: pack all weight matrices into MFMA B-fragment order (bf16) and fold
// the linear algebra:  M = eW2 @ nW[128:],  c = nb + eb2 @ nW[128:]
// ---------------------------------------------------------------------------
__global__ void prep_kernel(
    const float* __restrict__ e1W1, const float* __restrict__ e1b1,
    const float* __restrict__ e1W2, const float* __restrict__ e1b2,
    const float* __restrict__ n1W,  const float* __restrict__ n1b,
    const float* __restrict__ e2W1, const float* __restrict__ e2b1,
    const float* __restrict__ e2W2, const float* __restrict__ e2b2,
    const float* __restrict__ n2W,  const float* __restrict__ n2b,
    const float* __restrict__ muW,  const float* __restrict__ mub,
    const float* __restrict__ lvW,  const float* __restrict__ lvb,
    __bf16* __restrict__ packE, __bf16* __restrict__ packN1,
    __bf16* __restrict__ packN2, __bf16* __restrict__ packH,
    float* __restrict__ ebias, float* __restrict__ c1, float* __restrict__ c2,
    float* __restrict__ hbias)
{
    int bid = blockIdx.x;
    int lane = threadIdx.x;          // 64 threads
    int quad = lane >> 4, low = lane & 15;

    if (bid < 32) {                                   // edge B pack [64 x 256]
        int ct = bid >> 1, kt = bid & 1;
        for (int j = 0; j < 8; ++j) {
            int k = kt * 32 + quad * 8 + j;
            int n = ct * 16 + low;
            float v = (n < 128) ? e1W1[k * 128 + n] : e2W1[k * 128 + (n - 128)];
            packE[((ct * 2 + kt) * 64 + lane) * 8 + j] = (__bf16)v;
        }
    } else if (bid < 160) {                           // node1 / node2 B pack [256 x 128]
        bool is1 = bid < 96;
        int tile = bid - (is1 ? 32 : 96);
        const float* nW  = is1 ? n1W  : n2W;
        const float* eW2 = is1 ? e1W2 : e2W2;
        __bf16* dst = is1 ? packN1 : packN2;
        int ct = tile >> 3, kt = tile & 7;
        for (int j = 0; j < 8; ++j) {
            int k = kt * 32 + quad * 8 + j;
            int n = ct * 16 + low;
            float v;
            if (k < 128) {
                v = nW[k * 128 + n];
            } else {
                int i = k - 128;
                float acc = 0.f;
                for (int k2 = 0; k2 < 128; ++k2)
                    acc += eW2[i * 128 + k2] * nW[(128 + k2) * 128 + n];
                v = acc;
            }
            dst[((ct * 8 + kt) * 64 + lane) * 8 + j] = (__bf16)v;
        }
    } else if (bid < 192) {                           // head B pack [128 x 128]
        int tile = bid - 160;
        int ct = tile >> 2, kt = tile & 3;
        for (int j = 0; j < 8; ++j) {
            int k = kt * 32 + quad * 8 + j;
            int n = ct * 16 + low;
            float v = (n < 64) ? muW[k * 64 + n] : lvW[k * 64 + (n - 64)];
            packH[((ct * 4 + kt) * 64 + lane) * 8 + j] = (__bf16)v;
        }
    } else if (bid == 192 || bid == 193) {            // c1 / c2
        const float* nW  = (bid == 192) ? n1W  : n2W;
        const float* nb  = (bid == 192) ? n1b  : n2b;
        const float* eb2 = (bid == 192) ? e1b2 : e2b2;
        float* dst = (bid == 192) ? c1 : c2;
        for (int rep = 0; rep < 2; ++rep) {
            int j = lane + rep * 64;
            float acc = nb[j];
            for (int k = 0; k < 128; ++k)
                acc += eb2[k] * nW[(128 + k) * 128 + j];
            dst[j] = acc;
        }
    } else {                                          // biases
        for (int rep = 0; rep < 4; ++rep) {
            int j = lane + rep * 64;
            ebias[j] = (j < 128) ? e1b1[j] : e2b1[j - 128];
        }
        for (int rep = 0; rep < 2; ++rep) {
            int j = lane + rep * 64;
            hbias[j] = (j < 64) ? mub[j] : lvb[j - 64];
        }
    }
}

// --------------------------- counting sort by dst ---------------------------
__global__ void hist_kernel(const int* __restrict__ dstp, int* __restrict__ deg) {
    int e = blockIdx.x * 256 + threadIdx.x;
    if (e < N_EDGES) atomicAdd(&deg[dstp[e]], 1);
}

__global__ void scan_a(const int* __restrict__ deg, int* __restrict__ offs,
                       int* __restrict__ tileSum, float* __restrict__ degf) {
    __shared__ int s[512];
    int t = threadIdx.x, i = blockIdx.x * 512 + t;
    int v = (i < N_NODES) ? deg[i] : 0;
    if (i < N_NODES) degf[i] = (float)v;       // folded from old scan_c
    s[t] = v; __syncthreads();
    for (int off = 1; off < 512; off <<= 1) {
        int x = (t >= off) ? s[t - off] : 0;
        __syncthreads();
        s[t] += x;
        __syncthreads();
    }
    if (i < N_NODES) offs[i] = s[t] - v;       // exclusive within tile
    if (t == 511) tileSum[blockIdx.x] = s[511];
}

__global__ void scan_b(const int* __restrict__ tileSum, int* __restrict__ tileOff) {
    __shared__ int s[128];
    int t = threadIdx.x;
    int v = (t < NTILES) ? tileSum[t] : 0;
    s[t] = v; __syncthreads();
    for (int off = 1; off < 128; off <<= 1) {
        int x = (t >= off) ? s[t - off] : 0;
        __syncthreads();
        s[t] += x;
        __syncthreads();
    }
    if (t < NTILES) tileOff[t] = s[t] - v;
}

__global__ void scatter_kernel(const int* __restrict__ dstp, const int* __restrict__ offs,
                               const int* __restrict__ tileOff,
                               int* __restrict__ cursor, int* __restrict__ sorted,
                               int* __restrict__ sdst) {
    int e = blockIdx.x * 256 + threadIdx.x;
    if (e < N_EDGES) {
        int d = dstp[e];
        int p = offs[d] + tileOff[d >> 9] + atomicAdd(&cursor[d], 1);
        sorted[p] = e;
        sdst[p] = d;
    }
}

// ---------------------------------------------------------------------------
// Edge kernel v12: ONE TILE PER BLOCK — the anti-pipeline build.
// v8/v10 showed the 4-tile software pipeline's rotation registers are what
// keeps this kernel pinned at the spill cliff. v12 deletes the pipeline:
// grid = 10000 blocks x 1 tile. Latency hiding comes from TLP (4 blocks/CU).
//  * No bfragE hoist: each B-fragment is used once -> load inline from
//    L1-resident packE during GEMM1 (saves 32 VGPR of permanent live state).
//  * Run metadata in registers (ballot + popcll selector + ds_permute
//    run->dst table; correctness-proven in v9b/v10 passing runs).
//  * ONE barrier per block: publish As. Lb is wave-local; As never rewritten.
//  * LDS = 8192 (As, dedicated, swizzled) + 32768 (Lb) = 40960 B exactly
//    -> 4 blocks/CU at 160 KiB. __launch_bounds__(256, 4): peak live set
//    ~= C1 64 AGPR + inflight b-frags + addressing ~= 110 < 128.
//  * Swizzle byte ^= (row&7)<<4 (v9b/v10/v11-proven layout).
// ---------------------------------------------------------------------------
__global__ __launch_bounds__(256, 4) void edge_kernel(
    const float* __restrict__ edge_attr,
    const int* __restrict__ sorted, const int* __restrict__ sdst,
    const __bf16* __restrict__ packE,
    const float* __restrict__ ebias, float* __restrict__ S)
{
    __shared__ alignas(16) __bf16 As[64 * 64];         // 8192 B, swizzled
    __shared__ alignas(16) __bf16 Lball[4][64 * 64];   // 32768 B, per-wave slices

    int tid = threadIdx.x;
    int w = tid >> 6, lane = tid & 63;
    int quad = lane >> 4, low = lane & 15;
    int r = tid >> 2, c0 = (tid & 3) * 16;

    auto swz = [](int row, int cb) { return row * 128 + (cb ^ ((row & 7) << 4)); };

    char* AsB = reinterpret_cast<char*>(As);
    char* LbB = reinterpret_cast<char*>(&Lball[w][0]);

    int e0 = blockIdx.x * 64;

    // ---- load this block's 64-edge tile ----
    int ei = sorted[e0 + r];
    int md = sdst[e0 + lane];
    const float4* ap = reinterpret_cast<const float4*>(edge_attr + (size_t)ei * 64 + c0);
    float4 f0 = ap[0], f1 = ap[1], f2 = ap[2], f3 = ap[3];

    // ---- run structure in registers (all waves redundantly; v10-proven) ----
    int dp = __shfl_up(md, 1);
    bool flag = (lane > 0) && (md != dp);
    unsigned long long mask = __ballot(flag);
    int nruns = __popcll(mask) + 1;
    int rid = __popcll(mask & ((1ull << lane) - 1ull)) + (flag ? 1 : 0);
    int vdst = __builtin_amdgcn_ds_permute(rid << 2, md);   // lane j = dst of run j

    float bias_c[4];
    #pragma unroll
    for (int ct = 0; ct < 4; ++ct) bias_c[ct] = ebias[w * 64 + ct * 16 + low];

    // ---- stage As (bf16, swizzled stride-64) ----
    {
        bf16x8 v0, v1;
        v0[0]=(__bf16)f0.x; v0[1]=(__bf16)f0.y; v0[2]=(__bf16)f0.z; v0[3]=(__bf16)f0.w;
        v0[4]=(__bf16)f1.x; v0[5]=(__bf16)f1.y; v0[6]=(__bf16)f1.z; v0[7]=(__bf16)f1.w;
        v1[0]=(__bf16)f2.x; v1[1]=(__bf16)f2.y; v1[2]=(__bf16)f2.z; v1[3]=(__bf16)f2.w;
        v1[4]=(__bf16)f3.x; v1[5]=(__bf16)f3.y; v1[6]=(__bf16)f3.z; v1[7]=(__bf16)f3.w;
        *reinterpret_cast<bf16x8*>(AsB + swz(r, c0 * 2))      = v0;
        *reinterpret_cast<bf16x8*>(AsB + swz(r, c0 * 2 + 16)) = v1;
    }
    __syncthreads();                                   // As visible (only barrier)

    // ---- GEMM1: C1[rt][ct]; B-fragments loaded inline from L1 ----
    f32x4 C1[4][4] = {};
    #pragma unroll
    for (int kt = 0; kt < 2; ++kt)
        #pragma unroll
        for (int rt = 0; rt < 4; ++rt) {
            bf16x8 a = *reinterpret_cast<const bf16x8*>(
                AsB + swz(rt * 16 + low, kt * 64 + quad * 16));
            #pragma unroll
            for (int ct = 0; ct < 4; ++ct) {
                bf16x8 b = *reinterpret_cast<const bf16x8*>(
                    packE + (((w * 4 + ct) * 2 + kt) * 64 + lane) * 8);
                C1[rt][ct] = __builtin_amdgcn_mfma_f32_16x16x32_bf16(
                    a, b, C1[rt][ct], 0, 0, 0);
            }
        }

    // ---- epilogue: bias + leaky -> wave-local Lb (col-major, swizzled) ----
    #pragma unroll
    for (int rt = 0; rt < 4; ++rt)
        #pragma unroll
        for (int ct = 0; ct < 4; ++ct) {
            bf16x4 v;
            #pragma unroll
            for (int rr = 0; rr < 4; ++rr)
                v[rr] = (__bf16)leaky(C1[rt][ct][rr] + bias_c[ct]);
            *reinterpret_cast<bf16x4*>(
                LbB + swz(ct * 16 + low, rt * 32 + quad * 8)) = v;
        }

    // ---- GEMM2: S_part = R @ L, selector from mask; immediate atomics ----
    for (int rt2 = 0; rt2 * 16 < nruns; ++rt2) {
        int target = rt2 * 16 + low;
        f32x4 C2[4] = {};
        #pragma unroll
        for (int kt = 0; kt < 2; ++kt) {
            int bsh = 63 - kt * 32 - quad * 8;
            bf16x8 a;
            #pragma unroll
            for (int j = 0; j < 8; ++j) {
                int ride = __popcll(mask << (bsh - j));   // run id of edge kt*32+quad*8+j
                a[j] = (ride == target) ? (__bf16)1.0f : (__bf16)0.0f;
            }
            #pragma unroll
            for (int ct = 0; ct < 4; ++ct) {
                bf16x8 b = *reinterpret_cast<const bf16x8*>(
                    LbB + swz(ct * 16 + low, kt * 64 + quad * 16));
                C2[ct] = __builtin_amdgcn_mfma_f32_16x16x32_bf16(a, b, C2[ct], 0, 0, 0);
            }
        }
        int node4[4];
        #pragma unroll
        for (int rr = 0; rr < 4; ++rr)
            node4[rr] = __shfl(vdst, rt2 * 16 + quad * 4 + rr);
        #pragma unroll
        for (int ct = 0; ct < 4; ++ct) {
            int col = w * 64 + ct * 16 + low;
            #pragma unroll
            for (int rr = 0; rr < 4; ++rr) {
                int run = rt2 * 16 + quad * 4 + rr;
                if (run < nruns && (unsigned)node4[rr] < (unsigned)N_NODES)
                    unsafeAtomicAdd(&S[(size_t)node4[rr] * 256 + col], C2[ct][rr]);
            }
        }
    }
}

// ---------------------------------------------------------------------------
// Fused node pipeline: conv1 -> conv2 -> heads in ONE kernel.
// Row-local: h[r]=leaky(deg*x[r]@Wt1+deg*c1 + S1[r]@M1); same for g; out=g@[muW|lvW].
// h,g hand off through wave-local LDS (row-major bf16, stride 152).
// h is stored pre-scaled by deg (folds conv2's row scaling).
// ---------------------------------------------------------------------------
__global__ __launch_bounds__(256) void node_fused(
    const float* __restrict__ x, const float* __restrict__ S,
    const float* __restrict__ degf,
    const __bf16* __restrict__ packN1, const __bf16* __restrict__ packN2,
    const __bf16* __restrict__ packH,
    const float* __restrict__ c1, const float* __restrict__ c2,
    const float* __restrict__ hbias,
    float* __restrict__ out)
{
    constexpr int HS = 152;                        // row stride (elements), 304 B
    __shared__ __bf16 Hs[4][16 * HS];              // 19456 B
    int w = threadIdx.x >> 6, lane = threadIdx.x & 63;
    int quad = lane >> 4, low = lane & 15;
    int rb = blockIdx.x * 64 + w * 16;

    int arow = rb + low;
    if (arow >= N_NODES) arow = N_NODES - 1;
    float ds = degf[arow];
    const float* xrow = x + (size_t)arow * 128;
    const float* Srow = S + (size_t)arow * 256;

    float deg4[4];
    #pragma unroll
    for (int rr = 0; rr < 4; ++rr) {
        int row = rb + quad * 4 + rr;
        deg4[rr] = degf[row < N_NODES ? row : N_NODES - 1];
    }

    __bf16* Hw = Hs[w];

    // ---- conv1: C = [deg*x | S1] @ packN1 ----
    f32x4 C[8] = {};
    #pragma unroll
    for (int kt = 0; kt < 8; ++kt) {
        const float* base = (kt < 4) ? (xrow + kt * 32 + quad * 8)
                                     : (Srow + (kt - 4) * 32 + quad * 8);
        float4 p0 = *reinterpret_cast<const float4*>(base);
        float4 p1 = *reinterpret_cast<const float4*>(base + 4);
        float m = (kt < 4) ? ds : 1.f;
        bf16x8 a;
        a[0]=(__bf16)(p0.x*m); a[1]=(__bf16)(p0.y*m); a[2]=(__bf16)(p0.z*m); a[3]=(__bf16)(p0.w*m);
        a[4]=(__bf16)(p1.x*m); a[5]=(__bf16)(p1.y*m); a[6]=(__bf16)(p1.z*m); a[7]=(__bf16)(p1.w*m);
        #pragma unroll
        for (int ct = 0; ct < 8; ++ct) {
            bf16x8 b = *reinterpret_cast<const bf16x8*>(packN1 + ((ct * 8 + kt) * 64 + lane) * 8);
            C[ct] = __builtin_amdgcn_mfma_f32_16x16x32_bf16(a, b, C[ct], 0, 0, 0);
        }
    }
    // epilogue: store deg*h (pre-scaled for conv2) row-major bf16
    #pragma unroll
    for (int ct = 0; ct < 8; ++ct) {
        int col = ct * 16 + low;
        float cb = c1[col];
        #pragma unroll
        for (int rr = 0; rr < 4; ++rr) {
            float v = leaky(C[ct][rr] + deg4[rr] * cb);
            Hw[(quad * 4 + rr) * HS + col] = (__bf16)(v * deg4[rr]);
        }
    }

    // ---- conv2: C2 = [deg*h | S2] @ packN2 ----
    f32x4 C2[8] = {};
    #pragma unroll
    for (int kt = 0; kt < 8; ++kt) {
        bf16x8 a;
        if (kt < 4) {
            a = *reinterpret_cast<const bf16x8*>(&Hw[low * HS + kt * 32 + quad * 8]);
        } else {
            const float* base = Srow + 128 + (kt - 4) * 32 + quad * 8;
            float4 p0 = *reinterpret_cast<const float4*>(base);
            float4 p1 = *reinterpret_cast<const float4*>(base + 4);
            a[0]=(__bf16)p0.x; a[1]=(__bf16)p0.y; a[2]=(__bf16)p0.z; a[3]=(__bf16)p0.w;
            a[4]=(__bf16)p1.x; a[5]=(__bf16)p1.y; a[6]=(__bf16)p1.z; a[7]=(__bf16)p1.w;
        }
        #pragma unroll
        for (int ct = 0; ct < 8; ++ct) {
            bf16x8 b = *reinterpret_cast<const bf16x8*>(packN2 + ((ct * 8 + kt) * 64 + lane) * 8);
            C2[ct] = __builtin_amdgcn_mfma_f32_16x16x32_bf16(a, b, C2[ct], 0, 0, 0);
        }
    }
    // epilogue: store g (unscaled) over the same LDS
    #pragma unroll
    for (int ct = 0; ct < 8; ++ct) {
        int col = ct * 16 + low;
        float cb = c2[col];
        #pragma unroll
        for (int rr = 0; rr < 4; ++rr) {
            float v = leaky(C2[ct][rr] + deg4[rr] * cb);
            Hw[(quad * 4 + rr) * HS + col] = (__bf16)v;
        }
    }

    // ---- heads: C3 = g @ [muW|lvW] ----
    f32x4 C3[8] = {};
    #pragma unroll
    for (int kt = 0; kt < 4; ++kt) {
        bf16x8 a = *reinterpret_cast<const bf16x8*>(&Hw[low * HS + kt * 32 + quad * 8]);
        #pragma unroll
        for (int ct = 0; ct < 8; ++ct) {
            bf16x8 b = *reinterpret_cast<const bf16x8*>(packH + ((ct * 4 + kt) * 64 + lane) * 8);
            C3[ct] = __builtin_amdgcn_mfma_f32_16x16x32_bf16(a, b, C3[ct], 0, 0, 0);
        }
    }
    #pragma unroll
    for (int ct = 0; ct < 8; ++ct) {
        int col = ct * 16 + low;
        float hb = hbias[col];
        #pragma unroll
        for (int rr = 0; rr < 4; ++rr) {
            int row = rb + quad * 4 + rr;
            if (row >= N_NODES) continue;
            float v = C3[ct][rr] + hb;
            if (col < 64) out[(size_t)row * 64 + col] = v;
            else          out[(size_t)N_NODES * 64 + (size_t)row * 64 + (col - 64)] = v;
        }
    }
}

// ---------------------------------------------------------------------------
extern "C" void kernel_launch(void* const* d_in, const int* in_sizes, int n_in,
                              void* d_out, int out_size, void* d_ws, size_t ws_size,
                              hipStream_t stream)
{
    const float* x     = (const float*)d_in[0];
    const int*   eidx  = (const int*)  d_in[1];
    const float* eattr = (const float*)d_in[2];
    const float* e1W1 = (const float*)d_in[3];
    const float* e1b1 = (const float*)d_in[4];
    const float* e1W2 = (const float*)d_in[5];
    const float* e1b2 = (const float*)d_in[6];
    const float* n1W  = (const float*)d_in[7];
    const float* n1b  = (const float*)d_in[8];
    const float* e2W1 = (const float*)d_in[9];
    const float* e2b1 = (const float*)d_in[10];
    const float* e2W2 = (const float*)d_in[11];
    const float* e2b2 = (const float*)d_in[12];
    const float* n2W  = (const float*)d_in[13];
    const float* n2b  = (const float*)d_in[14];
    const float* muW  = (const float*)d_in[15];
    const float* mub  = (const float*)d_in[16];
    const float* lvW  = (const float*)d_in[17];
    const float* lvb  = (const float*)d_in[18];

    const int* dstp = eidx + N_EDGES;   // edge_index row 1

    char* ws = (char*)d_ws;
    size_t off = 0;
    auto alloc = [&](size_t bytes) -> void* {
        void* p = ws + off;
        off = (off + bytes + 1023) & ~(size_t)1023;
        return p;
    };
    float* S       = (float*)alloc((size_t)N_NODES * 256 * 4);   // [N][256] S1|S2
    float* h       = (float*)alloc((size_t)N_NODES * 128 * 4);   // unused (layout keep)
    float* g       = (float*)alloc((size_t)N_NODES * 128 * 4);   // backs sdst
    int*   deg     = (int*)  alloc((size_t)N_NODES * 4);
    int*   cursor  = (int*)  alloc((size_t)N_NODES * 4);
    int*   offs    = (int*)  alloc((size_t)N_NODES * 4);
    float* degf    = (float*)alloc((size_t)N_NODES * 4);
    int*   sorted  = (int*)  alloc((size_t)N_EDGES * 4);
    int*   tileSum = (int*)  alloc(NTILES * 4);
    int*   tileOff = (int*)  alloc(NTILES * 4);
    __bf16* packE  = (__bf16*)alloc(32 * 64 * 8 * 2);
    __bf16* packN1 = (__bf16*)alloc(64 * 64 * 8 * 2);
    __bf16* packN2 = (__bf16*)alloc(64 * 64 * 8 * 2);
    __bf16* packH  = (__bf16*)alloc(32 * 64 * 8 * 2);
    float* ebias   = (float*)alloc(256 * 4);
    float* c1      = (float*)alloc(128 * 4);
    float* c2      = (float*)alloc(128 * 4);
    float* hbias   = (float*)alloc(128 * 4);
    (void)ws_size; (void)in_sizes; (void)n_in; (void)out_size; (void)h;

    int* sdst = (int*)g;   // g region is free scratch (node pipeline fused)

    hipMemsetAsync(S, 0, (size_t)N_NODES * 256 * 4, stream);
    // deg + cursor are adjacent 1024-padded allocations -> one memset
    hipMemsetAsync(deg, 0, 2 * (((size_t)N_NODES * 4 + 1023) & ~(size_t)1023), stream);

    prep_kernel<<<195, 64, 0, stream>>>(e1W1, e1b1, e1W2, e1b2, n1W, n1b,
                                        e2W1, e2b1, e2W2, e2b2, n2W, n2b,
                                        muW, mub, lvW, lvb,
                                        packE, packN1, packN2, packH,
                                        ebias, c1, c2, hbias);

    hist_kernel<<<N_EDGES / 256, 256, 0, stream>>>(dstp, deg);
    scan_a<<<NTILES, 512, 0, stream>>>(deg, offs, tileSum, degf);
    scan_b<<<1, 128, 0, stream>>>(tileSum, tileOff);
    scatter_kernel<<<N_EDGES / 256, 256, 0, stream>>>(dstp, offs, tileOff, cursor, sorted, sdst);

    edge_kernel<<<N_EDGES / 64, 256, 0, stream>>>(eattr, sorted, sdst, packE, ebias, S);

    node_fused<<<(N_NODES + 63) / 64, 256, 0, stream>>>(
        x, S, degf, packN1, packN2, packH, c1, c2, hbias, (float*)d_out);
}